// Round 1
// baseline (771.563 us; speedup 1.0000x reference)
//
#include <hip/hip_runtime.h>
#include <math.h>

// Problem constants: B=1, T=2048, D=512, DS=32, EXP=2
#define T_LEN 2048
#define D_DIM 512
#define DS_DIM 32

__device__ __forceinline__ float silu_f(float x) { return x / (1.f + __expf(-x)); }
__device__ __forceinline__ float softplus_f(float x) {
  // jax.nn.softplus: logaddexp(x,0) == max(x,0) + log1p(exp(-|x|))
  return fmaxf(x, 0.f) + log1pf(__expf(-fabsf(x)));
}
__device__ __forceinline__ float gelu_f(float x) {
  // exact gelu (approximate=False)
  return 0.5f * x * (1.f + erff(x * 0.70710678118654752440f));
}

// ---------------------------------------------------------------------------
// RMSNorm: xn = x / sqrt(mean(x^2)+eps) * w   (one block per row, D=512)
// ---------------------------------------------------------------------------
__global__ __launch_bounds__(256) void rmsnorm_kernel(
    const float* __restrict__ x, const float* __restrict__ w,
    float* __restrict__ xn) {
  const int t = blockIdx.x;
  const float2 v = reinterpret_cast<const float2*>(x + (size_t)t * D_DIM)[threadIdx.x];
  float ss = v.x * v.x + v.y * v.y;
#pragma unroll
  for (int m = 1; m < 64; m <<= 1) ss += __shfl_xor(ss, m);
  __shared__ float wsum[4];
  if ((threadIdx.x & 63) == 0) wsum[threadIdx.x >> 6] = ss;
  __syncthreads();
  const float tot = wsum[0] + wsum[1] + wsum[2] + wsum[3];
  const float scale = rsqrtf(tot * (1.f / D_DIM) + 1e-6f);
  const float2 wv = reinterpret_cast<const float2*>(w)[threadIdx.x];
  float2 o;
  o.x = v.x * scale * wv.x;
  o.y = v.y * scale * wv.y;
  reinterpret_cast<float2*>(xn + (size_t)t * D_DIM)[threadIdx.x] = o;
}

// ---------------------------------------------------------------------------
// f32 SIMT GEMM: C[M,N] = act(A[M,K] @ B[K,N] + bias), optional C-accumulate.
// BM=BN=128, BK=16, 256 threads, 8x8 per-thread tile (2x2 blocks of 4x4).
// ACT: 0 = none, 1 = softplus, 2 = gelu(exact)
// ---------------------------------------------------------------------------
template <int ACT>
__global__ __launch_bounds__(256) void gemm128(
    const float* __restrict__ A, const float* __restrict__ B,
    float* __restrict__ C, int M, int N, int K,
    const float* __restrict__ bias, int accum) {
  __shared__ float As[16][128];  // As[k][m] (transposed A tile)
  __shared__ float Bs[16][128];  // Bs[k][n]
  const int tid = threadIdx.x;
  const int brow = blockIdx.y * 128;
  const int bcol = blockIdx.x * 128;
  const int r0 = (tid >> 4) << 2;   // 0..60
  const int c0 = (tid & 15) << 2;   // 0..60
  const int arow = tid >> 2;        // 0..63
  const int acol = (tid & 3) << 2;  // 0,4,8,12
  const int brr = tid >> 5;         // 0..7
  const int bcc = (tid & 31) << 2;  // 0..124

  float acc[8][8];
#pragma unroll
  for (int i = 0; i < 8; ++i)
#pragma unroll
    for (int j = 0; j < 8; ++j) acc[i][j] = 0.f;

  for (int k0 = 0; k0 < K; k0 += 16) {
#pragma unroll
    for (int p = 0; p < 2; ++p) {
      const int r = arow + p * 64;
      const float4 v = *reinterpret_cast<const float4*>(
          &A[(size_t)(brow + r) * K + k0 + acol]);
      As[acol + 0][r] = v.x;
      As[acol + 1][r] = v.y;
      As[acol + 2][r] = v.z;
      As[acol + 3][r] = v.w;
    }
#pragma unroll
    for (int p = 0; p < 2; ++p) {
      const int rr = brr + p * 8;
      *reinterpret_cast<float4*>(&Bs[rr][bcc]) = *reinterpret_cast<const float4*>(
          &B[(size_t)(k0 + rr) * N + bcol + bcc]);
    }
    __syncthreads();
#pragma unroll
    for (int kk = 0; kk < 16; ++kk) {
      const float4 a0 = *reinterpret_cast<const float4*>(&As[kk][r0]);
      const float4 a1 = *reinterpret_cast<const float4*>(&As[kk][r0 + 64]);
      const float4 b0 = *reinterpret_cast<const float4*>(&Bs[kk][c0]);
      const float4 b1 = *reinterpret_cast<const float4*>(&Bs[kk][c0 + 64]);
      const float av[8] = {a0.x, a0.y, a0.z, a0.w, a1.x, a1.y, a1.z, a1.w};
      const float bv[8] = {b0.x, b0.y, b0.z, b0.w, b1.x, b1.y, b1.z, b1.w};
#pragma unroll
      for (int i = 0; i < 8; ++i)
#pragma unroll
        for (int j = 0; j < 8; ++j)
          acc[i][j] = fmaf(av[i], bv[j], acc[i][j]);
    }
    __syncthreads();
  }

#pragma unroll
  for (int i = 0; i < 8; ++i) {
    const int row = brow + r0 + ((i >> 2) << 6) + (i & 3);
#pragma unroll
    for (int jh = 0; jh < 2; ++jh) {
      const int col = bcol + c0 + (jh << 6);
      float4 v = make_float4(acc[i][jh * 4 + 0], acc[i][jh * 4 + 1],
                             acc[i][jh * 4 + 2], acc[i][jh * 4 + 3]);
      if (bias) {
        v.x += bias[col + 0];
        v.y += bias[col + 1];
        v.z += bias[col + 2];
        v.w += bias[col + 3];
      }
      if (ACT == 1) {
        v.x = softplus_f(v.x); v.y = softplus_f(v.y);
        v.z = softplus_f(v.z); v.w = softplus_f(v.w);
      } else if (ACT == 2) {
        v.x = gelu_f(v.x); v.y = gelu_f(v.y);
        v.z = gelu_f(v.z); v.w = gelu_f(v.w);
      }
      float* cp = &C[(size_t)row * N + col];
      if (accum) {
        const float4 o = *reinterpret_cast<const float4*>(cp);
        v.x += o.x; v.y += o.y; v.z += o.z; v.w += o.w;
      }
      *reinterpret_cast<float4*>(cp) = v;
    }
  }
}

// ---------------------------------------------------------------------------
// Causal depthwise conv (k=4, left pad 3) + bias + SiLU.
// Input is xz[:, 0:512] (row stride 1024), output xs [T,512].
// ---------------------------------------------------------------------------
__global__ __launch_bounds__(256) void conv_silu_kernel(
    const float* __restrict__ xz, const float* __restrict__ cw,
    const float* __restrict__ cb, float* __restrict__ xs) {
  const int idx = blockIdx.x * 256 + threadIdx.x;  // t*512+d
  const int t = idx >> 9;
  const int d = idx & 511;
  const float4 w = reinterpret_cast<const float4*>(cw)[d];  // cw[d][0][0..3]
  float acc = cb[d];
  const float wk[4] = {w.x, w.y, w.z, w.w};
#pragma unroll
  for (int k = 0; k < 4; ++k) {
    const int tt = t - 3 + k;
    if (tt >= 0) acc = fmaf(xz[(size_t)tt * 1024 + d], wk[k], acc);
  }
  xs[idx] = silu_f(acc);
}

// ---------------------------------------------------------------------------
// Bm = xs @ W_B, Cm = xs @ W_C   (T x 32 each). One wave -> one row t,
// lanes 0..31 do B, 32..63 do C.
// ---------------------------------------------------------------------------
__global__ __launch_bounds__(256) void bc_kernel(
    const float* __restrict__ xs, const float* __restrict__ WB,
    const float* __restrict__ WC, float* __restrict__ Bm,
    float* __restrict__ Cm) {
  const int idx = blockIdx.x * 256 + threadIdx.x;
  const int t = idx >> 6;
  const int s = idx & 63;
  const float* __restrict__ W = (s < 32) ? WB : WC;
  const int col = s & 31;
  const float* __restrict__ xr = xs + (size_t)t * D_DIM;
  float acc = 0.f;
#pragma unroll 4
  for (int k = 0; k < D_DIM; k += 4) {
    const float4 xv = *reinterpret_cast<const float4*>(xr + k);
    acc = fmaf(xv.x, W[(k + 0) * 32 + col], acc);
    acc = fmaf(xv.y, W[(k + 1) * 32 + col], acc);
    acc = fmaf(xv.z, W[(k + 2) * 32 + col], acc);
    acc = fmaf(xv.w, W[(k + 3) * 32 + col], acc);
  }
  if (s < 32) Bm[t * 32 + col] = acc;
  else        Cm[t * 32 + col] = acc;
}

// ---------------------------------------------------------------------------
// Chunked SSM scan. One block per channel d; 512 threads = 16 chunks x 32 s.
// Chunk length 128. Recurrence h = exp(clip(dt*A)) * h + dt*xs*B; y = sum_s h*C.
// ---------------------------------------------------------------------------
__global__ __launch_bounds__(512) void ssm_scan_kernel(
    const float* __restrict__ xs, const float* __restrict__ dt,
    const float* __restrict__ Bm, const float* __restrict__ Cm,
    const float* __restrict__ log_A, float* __restrict__ y) {
  const int d = blockIdx.x;
  const int c = threadIdx.x >> 5;
  const int s = threadIdx.x & 31;
  const float A = -__expf(log_A[d]);

  __shared__ float hE[16][32];
  __shared__ float Pc[16];
  __shared__ float Hi[16][32];

  const int tbase = c * 128;
  // phase 1: local scan from zero state; track decay product
  float h = 0.f, prod = 1.f;
  for (int i = 0; i < 128; ++i) {
    const int t = tbase + i;
    const float dtv = dt[(size_t)t * D_DIM + d];
    const float xv = xs[(size_t)t * D_DIM + d];
    const float la = fminf(fmaxf(dtv * A, -20.f), 20.f);
    const float a = __expf(la);
    h = fmaf(a, h, dtv * xv * Bm[t * 32 + s]);
    prod *= a;
  }
  hE[c][s] = h;
  if (s == 0) Pc[c] = prod;
  __syncthreads();
  // phase 2: sequential combine over 16 chunks (lanes 0..31, one per s)
  if (threadIdx.x < 32) {
    float hh = 0.f;
    for (int cc = 0; cc < 16; ++cc) {
      Hi[cc][threadIdx.x] = hh;
      hh = fmaf(Pc[cc], hh, hE[cc][threadIdx.x]);
    }
  }
  __syncthreads();
  // phase 3: replay with correct initial state, emit y
  h = Hi[c][s];
  for (int i = 0; i < 128; ++i) {
    const int t = tbase + i;
    const float dtv = dt[(size_t)t * D_DIM + d];
    const float xv = xs[(size_t)t * D_DIM + d];
    const float la = fminf(fmaxf(dtv * A, -20.f), 20.f);
    const float a = __expf(la);
    h = fmaf(a, h, dtv * xv * Bm[t * 32 + s]);
    float p = h * Cm[t * 32 + s];
#pragma unroll
    for (int m = 16; m >= 1; m >>= 1) p += __shfl_xor(p, m);
    if (s == 0) y[(size_t)t * D_DIM + d] = p;
  }
}

// ---------------------------------------------------------------------------
// g = (y + xs*D_param) * silu(z)   (z = xz[:, 512:1024])
// ---------------------------------------------------------------------------
__global__ __launch_bounds__(256) void gate_kernel(
    const float* __restrict__ y, const float* __restrict__ xs,
    const float* __restrict__ Dp, const float* __restrict__ xz,
    float* __restrict__ g) {
  const int idx = blockIdx.x * 256 + threadIdx.x;
  const int t = idx >> 9;
  const int d = idx & 511;
  const float zv = xz[(size_t)t * 1024 + 512 + d];
  g[idx] = fmaf(xs[idx], Dp[d], y[idx]) * silu_f(zv);
}

__global__ __launch_bounds__(256) void copy_kernel(const float* __restrict__ src,
                                                   float* __restrict__ dst) {
  const int i = blockIdx.x * 256 + threadIdx.x;
  reinterpret_cast<float4*>(dst)[i] = reinterpret_cast<const float4*>(src)[i];
}

// ---------------------------------------------------------------------------
extern "C" void kernel_launch(void* const* d_in, const int* in_sizes, int n_in,
                              void* d_out, int out_size, void* d_ws, size_t ws_size,
                              hipStream_t stream) {
  const float* x      = (const float*)d_in[0];
  const float* norm_w = (const float*)d_in[1];
  const float* W_in   = (const float*)d_in[2];
  const float* conv_w = (const float*)d_in[3];
  const float* conv_b = (const float*)d_in[4];
  const float* W_dt   = (const float*)d_in[5];
  const float* b_dt   = (const float*)d_in[6];
  const float* W_B    = (const float*)d_in[7];
  const float* W_C    = (const float*)d_in[8];
  const float* W_out  = (const float*)d_in[9];
  const float* log_A  = (const float*)d_in[10];
  const float* D_par  = (const float*)d_in[11];
  const float* W_ffn1 = (const float*)d_in[12];
  const float* W_ffn2 = (const float*)d_in[13];
  const float* W_mrg  = (const float*)d_in[14];
  float* out = (float*)d_out;

  float* ws = (float*)d_ws;
  const size_t M1 = 1u << 20;  // T*D = 1M floats
  float* xn   = ws;            // 1M
  float* xz   = xn + M1;       // 2M
  float* xs   = xz + 2 * M1;   // 1M
  float* dt   = xs + M1;       // 1M
  float* Bm   = dt + M1;       // 64K
  float* Cm   = Bm + (1 << 16);
  float* yv   = Cm + (1 << 16);  // 1M
  float* g    = yv + M1;         // 1M
  float* yssm = g + M1;          // 1M
  float* h1   = yssm + M1;       // 2M
  float* yffn = h1 + 2 * M1;     // 1M   (total ~44.5 MB)

  // 1. RMSNorm
  rmsnorm_kernel<<<T_LEN, 256, 0, stream>>>(x, norm_w, xn);
  // 2. xz = xn @ W_in  [2048,1024]
  gemm128<0><<<dim3(8, 16), 256, 0, stream>>>(xn, W_in, xz, 2048, 1024, 512, nullptr, 0);
  // 3. xs = silu(causal_dwconv(xz[:, :512]) + conv_b)
  conv_silu_kernel<<<4096, 256, 0, stream>>>(xz, conv_w, conv_b, xs);
  // 4. dt = softplus(xs @ W_dt + b_dt)
  gemm128<1><<<dim3(4, 16), 256, 0, stream>>>(xs, W_dt, dt, 2048, 512, 512, b_dt, 0);
  // 5. Bm, Cm
  bc_kernel<<<512, 256, 0, stream>>>(xs, W_B, W_C, Bm, Cm);
  // 6. SSM scan
  ssm_scan_kernel<<<D_DIM, 512, 0, stream>>>(xs, dt, Bm, Cm, log_A, yv);
  // 7. gate: g = (y + xs*D)*silu(z)
  gate_kernel<<<4096, 256, 0, stream>>>(yv, xs, D_par, xz, g);
  // 8. y_ssm = g @ W_out
  gemm128<0><<<dim3(4, 16), 256, 0, stream>>>(g, W_out, yssm, 2048, 512, 512, nullptr, 0);
  // 9. h1 = gelu(xn @ W_ffn1)
  gemm128<2><<<dim3(8, 16), 256, 0, stream>>>(xn, W_ffn1, h1, 2048, 1024, 512, nullptr, 0);
  // 10. y_ffn = h1 @ W_ffn2
  gemm128<0><<<dim3(4, 16), 256, 0, stream>>>(h1, W_ffn2, yffn, 2048, 512, 1024, nullptr, 0);
  // 11. out = x; out += y_ssm @ W_merge[:512]; out += y_ffn @ W_merge[512:]
  copy_kernel<<<1024, 256, 0, stream>>>(x, out);
  gemm128<0><<<dim3(4, 16), 256, 0, stream>>>(yssm, W_mrg, out, 2048, 512, 512, nullptr, 1);
  gemm128<0><<<dim3(4, 16), 256, 0, stream>>>(yffn, W_mrg + 512 * 512, out, 2048, 512, 512, nullptr, 1);
}

// Round 2
// 203.988 us; speedup vs baseline: 3.7824x; 3.7824x over previous
//
#include <hip/hip_runtime.h>
#include <math.h>

// Problem constants: B=1, T=2048, D=512, DS=32, EXP=2
#define T_LEN 2048
#define D_DIM 512

typedef __bf16 bf16x8 __attribute__((ext_vector_type(8)));
typedef float f32x4 __attribute__((ext_vector_type(4)));

__device__ __forceinline__ float silu_f(float x) { return x / (1.f + __expf(-x)); }
__device__ __forceinline__ float softplus_f(float x) {
  return fmaxf(x, 0.f) + log1pf(__expf(-fabsf(x)));
}
__device__ __forceinline__ float gelu_f(float x) {
  return 0.5f * x * (1.f + erff(x * 0.70710678118654752440f));
}
__device__ __forceinline__ unsigned short f2bf(float f) {
  union { float f; unsigned u; } v; v.f = f;
  unsigned r = v.u + 0x7FFF + ((v.u >> 16) & 1);  // round-nearest-even
  return (unsigned short)(r >> 16);
}

// ---------------------------------------------------------------------------
// RMSNorm -> bf16 output (only consumed as GEMM A operand)
// ---------------------------------------------------------------------------
__global__ __launch_bounds__(256) void rmsnorm_kernel(
    const float* __restrict__ x, const float* __restrict__ w,
    unsigned short* __restrict__ xn) {
  const int t = blockIdx.x;
  const float2 v = reinterpret_cast<const float2*>(x + (size_t)t * D_DIM)[threadIdx.x];
  float ss = v.x * v.x + v.y * v.y;
#pragma unroll
  for (int m = 1; m < 64; m <<= 1) ss += __shfl_xor(ss, m);
  __shared__ float wsum[4];
  if ((threadIdx.x & 63) == 0) wsum[threadIdx.x >> 6] = ss;
  __syncthreads();
  const float tot = wsum[0] + wsum[1] + wsum[2] + wsum[3];
  const float scale = rsqrtf(tot * (1.f / D_DIM) + 1e-6f);
  const float2 wv = reinterpret_cast<const float2*>(w)[threadIdx.x];
  ushort2 o;
  o.x = f2bf(v.x * scale * wv.x);
  o.y = f2bf(v.y * scale * wv.y);
  reinterpret_cast<ushort2*>(xn + (size_t)t * D_DIM)[threadIdx.x] = o;
}

// ---------------------------------------------------------------------------
// Weight transpose + f32->bf16: src f32 [K,N] row-major -> dst bf16 [N,K]
// ---------------------------------------------------------------------------
__global__ __launch_bounds__(256) void transpose_bf16_kernel(
    const float* __restrict__ src, unsigned short* __restrict__ dst,
    int K, int N) {
  __shared__ float tile[32][33];
  const int k0 = blockIdx.y * 32, n0 = blockIdx.x * 32;
  const int i = threadIdx.x & 31;
  const int r = threadIdx.x >> 5;  // 0..7
#pragma unroll
  for (int p = 0; p < 4; ++p) {
    const int kk = r + p * 8;
    tile[kk][i] = src[(size_t)(k0 + kk) * N + n0 + i];
  }
  __syncthreads();
#pragma unroll
  for (int p = 0; p < 4; ++p) {
    const int nn = r + p * 8;
    dst[(size_t)(n0 + nn) * K + k0 + i] = f2bf(tile[i][nn]);
  }
}

// ---------------------------------------------------------------------------
// bf16 MFMA GEMM: C[M,N] = act(A[M,K] @ Bt[N,K]^T + bias)
// A bf16 row-major, Bt bf16 row-major ([N,K] = B^T). 64x64 tile, BK=64,
// 256 threads = 4 waves, each wave owns a 32x32 quadrant (2x2 16x16 frags).
// XOR-swizzled LDS (slot ^ (row&7)) => conflict-free ds_read_b128.
// ACT: 0 none, 1 softplus, 2 gelu. OUTBF: write bf16 (else f32).
// ACC: f32 C += (read-modify-write).
// ---------------------------------------------------------------------------
template <int ACT, int OUTBF, int ACC>
__global__ __launch_bounds__(256) void gemm_mfma(
    const unsigned short* __restrict__ Abf, const unsigned short* __restrict__ Btbf,
    void* __restrict__ Cout, int M, int N, int K,
    const float* __restrict__ bias) {
  __shared__ bf16x8 As[512];  // 64 rows x 8 slots (16B each)
  __shared__ bf16x8 Bs[512];

  const int tid = threadIdx.x;
  const int lane = tid & 63;
  const int w = tid >> 6;            // wave 0..3
  const int wrow = (w >> 1) * 32;
  const int wcol = (w & 1) * 32;
  const int brow = blockIdx.y * 64;
  const int bcol = blockIdx.x * 64;
  const int K8 = K >> 3;

  const bf16x8* __restrict__ A8 = reinterpret_cast<const bf16x8*>(Abf);
  const bf16x8* __restrict__ B8 = reinterpret_cast<const bf16x8*>(Btbf);

  // staging indices: idx = p*256+tid -> row idx>>3, slot idx&7
  const int r0s = tid >> 3;          // rows 0..31 (p=0), +32 (p=1)
  const int c0s = tid & 7;

  f32x4 acc[2][2];
#pragma unroll
  for (int m = 0; m < 2; ++m)
#pragma unroll
    for (int n = 0; n < 2; ++n) acc[m][n] = {0.f, 0.f, 0.f, 0.f};

  const int nt = K >> 6;  // BK = 64
  bf16x8 pa[2], pb[2];
  // prefetch tile 0
#pragma unroll
  for (int p = 0; p < 2; ++p) {
    const int rr = r0s + p * 32;
    pa[p] = A8[(size_t)(brow + rr) * K8 + c0s];
    pb[p] = B8[(size_t)(bcol + rr) * K8 + c0s];
  }

  for (int t = 0; t < nt; ++t) {
#pragma unroll
    for (int p = 0; p < 2; ++p) {
      const int rr = r0s + p * 32;
      As[rr * 8 + (c0s ^ (rr & 7))] = pa[p];
      Bs[rr * 8 + (c0s ^ (rr & 7))] = pb[p];
    }
    __syncthreads();
    if (t + 1 < nt) {
      const int kb = (t + 1) * 8;
#pragma unroll
      for (int p = 0; p < 2; ++p) {
        const int rr = r0s + p * 32;
        pa[p] = A8[(size_t)(brow + rr) * K8 + kb + c0s];
        pb[p] = B8[(size_t)(bcol + rr) * K8 + kb + c0s];
      }
    }
#pragma unroll
    for (int kk = 0; kk < 2; ++kk) {
      const int slot = kk * 4 + (lane >> 4);
      bf16x8 af[2], bf_[2];
#pragma unroll
      for (int m = 0; m < 2; ++m) {
        const int r = wrow + m * 16 + (lane & 15);
        af[m] = As[r * 8 + (slot ^ (r & 7))];
      }
#pragma unroll
      for (int n = 0; n < 2; ++n) {
        const int r = wcol + n * 16 + (lane & 15);
        bf_[n] = Bs[r * 8 + (slot ^ (r & 7))];
      }
#pragma unroll
      for (int m = 0; m < 2; ++m)
#pragma unroll
        for (int n = 0; n < 2; ++n)
          acc[m][n] = __builtin_amdgcn_mfma_f32_16x16x32_bf16(af[m], bf_[n], acc[m][n], 0, 0, 0);
    }
    __syncthreads();
  }

  // epilogue: D elem (row,col): col = lane&15, row = (lane>>4)*4 + j
#pragma unroll
  for (int m = 0; m < 2; ++m) {
#pragma unroll
    for (int n = 0; n < 2; ++n) {
      const int col = bcol + wcol + n * 16 + (lane & 15);
      const float bv = bias ? bias[col] : 0.f;
#pragma unroll
      for (int j = 0; j < 4; ++j) {
        const int row = brow + wrow + m * 16 + (lane >> 4) * 4 + j;
        float v = acc[m][n][j] + bv;
        if (ACT == 1) v = softplus_f(v);
        else if (ACT == 2) v = gelu_f(v);
        if (OUTBF) {
          reinterpret_cast<unsigned short*>(Cout)[(size_t)row * N + col] = f2bf(v);
        } else {
          float* cp = reinterpret_cast<float*>(Cout) + (size_t)row * N + col;
          if (ACC) v += *cp;
          *cp = v;
        }
      }
    }
  }
}

// ---------------------------------------------------------------------------
// Causal depthwise conv (k=4, left pad 3) + bias + SiLU. Writes f32 + bf16.
// ---------------------------------------------------------------------------
__global__ __launch_bounds__(256) void conv_silu_kernel(
    const float* __restrict__ xz, const float* __restrict__ cw,
    const float* __restrict__ cb, float* __restrict__ xs,
    unsigned short* __restrict__ xs_bf) {
  const int idx = blockIdx.x * 256 + threadIdx.x;  // t*512+d
  const int t = idx >> 9;
  const int d = idx & 511;
  const float4 w = reinterpret_cast<const float4*>(cw)[d];
  float acc = cb[d];
  const float wk[4] = {w.x, w.y, w.z, w.w};
#pragma unroll
  for (int k = 0; k < 4; ++k) {
    const int tt = t - 3 + k;
    if (tt >= 0) acc = fmaf(xz[(size_t)tt * 1024 + d], wk[k], acc);
  }
  const float s = silu_f(acc);
  xs[idx] = s;
  xs_bf[idx] = f2bf(s);
}

// ---------------------------------------------------------------------------
// Bm = xs @ W_B, Cm = xs @ W_C (f32, tiny N=32)
// ---------------------------------------------------------------------------
__global__ __launch_bounds__(256) void bc_kernel(
    const float* __restrict__ xs, const float* __restrict__ WB,
    const float* __restrict__ WC, float* __restrict__ Bm,
    float* __restrict__ Cm) {
  const int idx = blockIdx.x * 256 + threadIdx.x;
  const int t = idx >> 6;
  const int s = idx & 63;
  const float* __restrict__ W = (s < 32) ? WB : WC;
  const int col = s & 31;
  const float* __restrict__ xr = xs + (size_t)t * D_DIM;
  float acc = 0.f;
#pragma unroll 4
  for (int k = 0; k < D_DIM; k += 4) {
    const float4 xv = *reinterpret_cast<const float4*>(xr + k);
    acc = fmaf(xv.x, W[(k + 0) * 32 + col], acc);
    acc = fmaf(xv.y, W[(k + 1) * 32 + col], acc);
    acc = fmaf(xv.z, W[(k + 2) * 32 + col], acc);
    acc = fmaf(xv.w, W[(k + 3) * 32 + col], acc);
  }
  if (s < 32) Bm[t * 32 + col] = acc;
  else        Cm[t * 32 + col] = acc;
}

// ---------------------------------------------------------------------------
// Chunked SSM scan (f32). One block per d; 16 chunks x 32 states.
// ---------------------------------------------------------------------------
__global__ __launch_bounds__(512) void ssm_scan_kernel(
    const float* __restrict__ xs, const float* __restrict__ dt,
    const float* __restrict__ Bm, const float* __restrict__ Cm,
    const float* __restrict__ log_A, float* __restrict__ y) {
  const int d = blockIdx.x;
  const int c = threadIdx.x >> 5;
  const int s = threadIdx.x & 31;
  const float A = -__expf(log_A[d]);

  __shared__ float hE[16][32];
  __shared__ float Pc[16];
  __shared__ float Hi[16][32];

  const int tbase = c * 128;
  float h = 0.f, prod = 1.f;
  for (int i = 0; i < 128; ++i) {
    const int t = tbase + i;
    const float dtv = dt[(size_t)t * D_DIM + d];
    const float xv = xs[(size_t)t * D_DIM + d];
    const float la = fminf(fmaxf(dtv * A, -20.f), 20.f);
    const float a = __expf(la);
    h = fmaf(a, h, dtv * xv * Bm[t * 32 + s]);
    prod *= a;
  }
  hE[c][s] = h;
  if (s == 0) Pc[c] = prod;
  __syncthreads();
  if (threadIdx.x < 32) {
    float hh = 0.f;
    for (int cc = 0; cc < 16; ++cc) {
      Hi[cc][threadIdx.x] = hh;
      hh = fmaf(Pc[cc], hh, hE[cc][threadIdx.x]);
    }
  }
  __syncthreads();
  h = Hi[c][s];
  for (int i = 0; i < 128; ++i) {
    const int t = tbase + i;
    const float dtv = dt[(size_t)t * D_DIM + d];
    const float xv = xs[(size_t)t * D_DIM + d];
    const float la = fminf(fmaxf(dtv * A, -20.f), 20.f);
    const float a = __expf(la);
    h = fmaf(a, h, dtv * xv * Bm[t * 32 + s]);
    float p = h * Cm[t * 32 + s];
#pragma unroll
    for (int m = 16; m >= 1; m >>= 1) p += __shfl_xor(p, m);
    if (s == 0) y[(size_t)t * D_DIM + d] = p;
  }
}

// ---------------------------------------------------------------------------
// g = (y + xs*D_param) * silu(z) -> bf16
// ---------------------------------------------------------------------------
__global__ __launch_bounds__(256) void gate_kernel(
    const float* __restrict__ y, const float* __restrict__ xs,
    const float* __restrict__ Dp, const float* __restrict__ xz,
    unsigned short* __restrict__ g) {
  const int idx = blockIdx.x * 256 + threadIdx.x;
  const int t = idx >> 9;
  const int d = idx & 511;
  const float zv = xz[(size_t)t * 1024 + 512 + d];
  g[idx] = f2bf(fmaf(xs[idx], Dp[d], y[idx]) * silu_f(zv));
}

__global__ __launch_bounds__(256) void copy_kernel(const float* __restrict__ src,
                                                   float* __restrict__ dst) {
  const int i = blockIdx.x * 256 + threadIdx.x;
  reinterpret_cast<float4*>(dst)[i] = reinterpret_cast<const float4*>(src)[i];
}

// ---------------------------------------------------------------------------
extern "C" void kernel_launch(void* const* d_in, const int* in_sizes, int n_in,
                              void* d_out, int out_size, void* d_ws, size_t ws_size,
                              hipStream_t stream) {
  const float* x      = (const float*)d_in[0];
  const float* norm_w = (const float*)d_in[1];
  const float* W_in   = (const float*)d_in[2];
  const float* conv_w = (const float*)d_in[3];
  const float* conv_b = (const float*)d_in[4];
  const float* W_dt   = (const float*)d_in[5];
  const float* b_dt   = (const float*)d_in[6];
  const float* W_B    = (const float*)d_in[7];
  const float* W_C    = (const float*)d_in[8];
  const float* W_out  = (const float*)d_in[9];
  const float* log_A  = (const float*)d_in[10];
  const float* D_par  = (const float*)d_in[11];
  const float* W_ffn1 = (const float*)d_in[12];
  const float* W_ffn2 = (const float*)d_in[13];
  const float* W_mrg  = (const float*)d_in[14];
  float* out = (float*)d_out;

  const size_t M1 = 1u << 20;  // T*D elements
  char* ws = (char*)d_ws;
  size_t off = 0;
  auto alloc_f = [&](size_t n) { float* p = (float*)(ws + off); off += n * 4; return p; };
  auto alloc_h = [&](size_t n) { unsigned short* p = (unsigned short*)(ws + off); off += n * 2; return p; };

  float* xz = alloc_f(2 * M1);
  float* xs = alloc_f(M1);
  float* dt = alloc_f(M1);
  float* yv = alloc_f(M1);
  float* Bm = alloc_f(1 << 16);
  float* Cm = alloc_f(1 << 16);
  unsigned short* xn_bf   = alloc_h(M1);
  unsigned short* xs_bf   = alloc_h(M1);
  unsigned short* g_bf    = alloc_h(M1);
  unsigned short* h1_bf   = alloc_h(2 * M1);
  unsigned short* yssm_bf = alloc_h(M1);
  unsigned short* yffn_bf = alloc_h(M1);
  unsigned short* WinT  = alloc_h(512 * 1024);
  unsigned short* WdtT  = alloc_h(512 * 512);
  unsigned short* WoutT = alloc_h(512 * 512);
  unsigned short* Wf1T  = alloc_h(512 * 1024);
  unsigned short* Wf2T  = alloc_h(512 * 1024);
  unsigned short* Wm1T  = alloc_h(512 * 512);
  unsigned short* Wm2T  = alloc_h(512 * 512);

  // --- weight prep: transpose + convert to bf16 [N,K] ---
  transpose_bf16_kernel<<<dim3(32, 16), 256, 0, stream>>>(W_in,   WinT, 512, 1024);
  transpose_bf16_kernel<<<dim3(16, 16), 256, 0, stream>>>(W_dt,   WdtT, 512, 512);
  transpose_bf16_kernel<<<dim3(16, 16), 256, 0, stream>>>(W_out,  WoutT, 512, 512);
  transpose_bf16_kernel<<<dim3(32, 16), 256, 0, stream>>>(W_ffn1, Wf1T, 512, 1024);
  transpose_bf16_kernel<<<dim3(16, 32), 256, 0, stream>>>(W_ffn2, Wf2T, 1024, 512);
  transpose_bf16_kernel<<<dim3(16, 16), 256, 0, stream>>>(W_mrg,             Wm1T, 512, 512);
  transpose_bf16_kernel<<<dim3(16, 16), 256, 0, stream>>>(W_mrg + 512 * 512, Wm2T, 512, 512);

  // 1. RMSNorm -> bf16
  rmsnorm_kernel<<<T_LEN, 256, 0, stream>>>(x, norm_w, xn_bf);
  // 2. xz = xn @ W_in  (f32 out)
  gemm_mfma<0, 0, 0><<<dim3(16, 32), 256, 0, stream>>>(xn_bf, WinT, xz, 2048, 1024, 512, nullptr);
  // 3. conv + silu -> xs (f32 + bf16)
  conv_silu_kernel<<<4096, 256, 0, stream>>>(xz, conv_w, conv_b, xs, xs_bf);
  // 4. dt = softplus(xs @ W_dt + b_dt) (f32)
  gemm_mfma<1, 0, 0><<<dim3(8, 32), 256, 0, stream>>>(xs_bf, WdtT, dt, 2048, 512, 512, b_dt);
  // 5. Bm, Cm (f32)
  bc_kernel<<<512, 256, 0, stream>>>(xs, W_B, W_C, Bm, Cm);
  // 6. SSM scan
  ssm_scan_kernel<<<D_DIM, 512, 0, stream>>>(xs, dt, Bm, Cm, log_A, yv);
  // 7. gate -> bf16
  gate_kernel<<<4096, 256, 0, stream>>>(yv, xs, D_par, xz, g_bf);
  // 8. y_ssm = g @ W_out -> bf16
  gemm_mfma<0, 1, 0><<<dim3(8, 32), 256, 0, stream>>>(g_bf, WoutT, yssm_bf, 2048, 512, 512, nullptr);
  // 9. h1 = gelu(xn @ W_ffn1) -> bf16
  gemm_mfma<2, 1, 0><<<dim3(16, 32), 256, 0, stream>>>(xn_bf, Wf1T, h1_bf, 2048, 1024, 512, nullptr);
  // 10. y_ffn = h1 @ W_ffn2 -> bf16
  gemm_mfma<0, 1, 0><<<dim3(8, 32), 256, 0, stream>>>(h1_bf, Wf2T, yffn_bf, 2048, 512, 1024, nullptr);
  // 11. out = x + y_ssm @ Wm1 + y_ffn @ Wm2
  copy_kernel<<<1024, 256, 0, stream>>>(x, out);
  gemm_mfma<0, 0, 1><<<dim3(8, 32), 256, 0, stream>>>(yssm_bf, Wm1T, out, 2048, 512, 512, nullptr);
  gemm_mfma<0, 0, 1><<<dim3(8, 32), 256, 0, stream>>>(yffn_bf, Wm2T, out, 2048, 512, 512, nullptr);
}

// Round 3
// 198.067 us; speedup vs baseline: 3.8955x; 1.0299x over previous
//
#include <hip/hip_runtime.h>
#include <math.h>

// Problem constants: B=1, T=2048, D=512, DS=32, EXP=2
#define T_LEN 2048
#define D_DIM 512

typedef __bf16 bf16x8 __attribute__((ext_vector_type(8)));
typedef float f32x4 __attribute__((ext_vector_type(4)));

__device__ __forceinline__ float silu_f(float x) { return x / (1.f + __expf(-x)); }
__device__ __forceinline__ float softplus_f(float x) {
  return fmaxf(x, 0.f) + log1pf(__expf(-fabsf(x)));
}
__device__ __forceinline__ float gelu_f(float x) {
  return 0.5f * x * (1.f + erff(x * 0.70710678118654752440f));
}
__device__ __forceinline__ unsigned short f2bf(float f) {
  union { float f; unsigned u; } v; v.f = f;
  unsigned r = v.u + 0x7FFF + ((v.u >> 16) & 1);  // round-nearest-even
  return (unsigned short)(r >> 16);
}

// ---------------------------------------------------------------------------
// RMSNorm -> bf16 output (only consumed as GEMM A operand)
// ---------------------------------------------------------------------------
__global__ __launch_bounds__(256) void rmsnorm_kernel(
    const float* __restrict__ x, const float* __restrict__ w,
    unsigned short* __restrict__ xn) {
  const int t = blockIdx.x;
  const float2 v = reinterpret_cast<const float2*>(x + (size_t)t * D_DIM)[threadIdx.x];
  float ss = v.x * v.x + v.y * v.y;
#pragma unroll
  for (int m = 1; m < 64; m <<= 1) ss += __shfl_xor(ss, m);
  __shared__ float wsum[4];
  if ((threadIdx.x & 63) == 0) wsum[threadIdx.x >> 6] = ss;
  __syncthreads();
  const float tot = wsum[0] + wsum[1] + wsum[2] + wsum[3];
  const float scale = rsqrtf(tot * (1.f / D_DIM) + 1e-6f);
  const float2 wv = reinterpret_cast<const float2*>(w)[threadIdx.x];
  ushort2 o;
  o.x = f2bf(v.x * scale * wv.x);
  o.y = f2bf(v.y * scale * wv.y);
  reinterpret_cast<ushort2*>(xn + (size_t)t * D_DIM)[threadIdx.x] = o;
}

// ---------------------------------------------------------------------------
// Weight transpose + f32->bf16: src f32 [K,N] row-major -> dst bf16 [N,K]
// ---------------------------------------------------------------------------
__global__ __launch_bounds__(256) void transpose_bf16_kernel(
    const float* __restrict__ src, unsigned short* __restrict__ dst,
    int K, int N) {
  __shared__ float tile[32][33];
  const int k0 = blockIdx.y * 32, n0 = blockIdx.x * 32;
  const int i = threadIdx.x & 31;
  const int r = threadIdx.x >> 5;  // 0..7
#pragma unroll
  for (int p = 0; p < 4; ++p) {
    const int kk = r + p * 8;
    tile[kk][i] = src[(size_t)(k0 + kk) * N + n0 + i];
  }
  __syncthreads();
#pragma unroll
  for (int p = 0; p < 4; ++p) {
    const int nn = r + p * 8;
    dst[(size_t)(n0 + nn) * K + k0 + i] = f2bf(tile[i][nn]);
  }
}

// ---------------------------------------------------------------------------
// bf16 MFMA GEMM: C[M,N] = act(A[M,K] @ Bt[N,K]^T + bias)
// 64x64 tile, BK=64, 4 waves each own a 32x32 quadrant. XOR-swizzled LDS.
// ACT: 0 none, 1 softplus, 2 gelu. OUTBF: bf16 out. ACC: f32 C += RMW.
// ---------------------------------------------------------------------------
template <int ACT, int OUTBF, int ACC>
__global__ __launch_bounds__(256) void gemm_mfma(
    const unsigned short* __restrict__ Abf, const unsigned short* __restrict__ Btbf,
    void* __restrict__ Cout, int M, int N, int K,
    const float* __restrict__ bias) {
  __shared__ bf16x8 As[512];  // 64 rows x 8 slots (16B each)
  __shared__ bf16x8 Bs[512];

  const int tid = threadIdx.x;
  const int lane = tid & 63;
  const int w = tid >> 6;            // wave 0..3
  const int wrow = (w >> 1) * 32;
  const int wcol = (w & 1) * 32;
  const int brow = blockIdx.y * 64;
  const int bcol = blockIdx.x * 64;
  const int K8 = K >> 3;

  const bf16x8* __restrict__ A8 = reinterpret_cast<const bf16x8*>(Abf);
  const bf16x8* __restrict__ B8 = reinterpret_cast<const bf16x8*>(Btbf);

  const int r0s = tid >> 3;          // rows 0..31 (p=0), +32 (p=1)
  const int c0s = tid & 7;

  f32x4 acc[2][2];
#pragma unroll
  for (int m = 0; m < 2; ++m)
#pragma unroll
    for (int n = 0; n < 2; ++n) acc[m][n] = {0.f, 0.f, 0.f, 0.f};

  const int nt = K >> 6;  // BK = 64
  bf16x8 pa[2], pb[2];
#pragma unroll
  for (int p = 0; p < 2; ++p) {
    const int rr = r0s + p * 32;
    pa[p] = A8[(size_t)(brow + rr) * K8 + c0s];
    pb[p] = B8[(size_t)(bcol + rr) * K8 + c0s];
  }

  for (int t = 0; t < nt; ++t) {
#pragma unroll
    for (int p = 0; p < 2; ++p) {
      const int rr = r0s + p * 32;
      As[rr * 8 + (c0s ^ (rr & 7))] = pa[p];
      Bs[rr * 8 + (c0s ^ (rr & 7))] = pb[p];
    }
    __syncthreads();
    if (t + 1 < nt) {
      const int kb = (t + 1) * 8;
#pragma unroll
      for (int p = 0; p < 2; ++p) {
        const int rr = r0s + p * 32;
        pa[p] = A8[(size_t)(brow + rr) * K8 + kb + c0s];
        pb[p] = B8[(size_t)(bcol + rr) * K8 + kb + c0s];
      }
    }
#pragma unroll
    for (int kk = 0; kk < 2; ++kk) {
      const int slot = kk * 4 + (lane >> 4);
      bf16x8 af[2], bf_[2];
#pragma unroll
      for (int m = 0; m < 2; ++m) {
        const int r = wrow + m * 16 + (lane & 15);
        af[m] = As[r * 8 + (slot ^ (r & 7))];
      }
#pragma unroll
      for (int n = 0; n < 2; ++n) {
        const int r = wcol + n * 16 + (lane & 15);
        bf_[n] = Bs[r * 8 + (slot ^ (r & 7))];
      }
#pragma unroll
      for (int m = 0; m < 2; ++m)
#pragma unroll
        for (int n = 0; n < 2; ++n)
          acc[m][n] = __builtin_amdgcn_mfma_f32_16x16x32_bf16(af[m], bf_[n], acc[m][n], 0, 0, 0);
    }
    __syncthreads();
  }

#pragma unroll
  for (int m = 0; m < 2; ++m) {
#pragma unroll
    for (int n = 0; n < 2; ++n) {
      const int col = bcol + wcol + n * 16 + (lane & 15);
      const float bv = bias ? bias[col] : 0.f;
#pragma unroll
      for (int j = 0; j < 4; ++j) {
        const int row = brow + wrow + m * 16 + (lane >> 4) * 4 + j;
        float v = acc[m][n][j] + bv;
        if (ACT == 1) v = softplus_f(v);
        else if (ACT == 2) v = gelu_f(v);
        if (OUTBF) {
          reinterpret_cast<unsigned short*>(Cout)[(size_t)row * N + col] = f2bf(v);
        } else {
          float* cp = reinterpret_cast<float*>(Cout) + (size_t)row * N + col;
          if (ACC) v += *cp;
          *cp = v;
        }
      }
    }
  }
}

// ---------------------------------------------------------------------------
// Causal depthwise conv (k=4, left pad 3) + bias + SiLU. Writes f32 + bf16.
// ---------------------------------------------------------------------------
__global__ __launch_bounds__(256) void conv_silu_kernel(
    const float* __restrict__ xz, const float* __restrict__ cw,
    const float* __restrict__ cb, float* __restrict__ xs,
    unsigned short* __restrict__ xs_bf) {
  const int idx = blockIdx.x * 256 + threadIdx.x;  // t*512+d
  const int t = idx >> 9;
  const int d = idx & 511;
  const float4 w = reinterpret_cast<const float4*>(cw)[d];
  float acc = cb[d];
  const float wk[4] = {w.x, w.y, w.z, w.w};
#pragma unroll
  for (int k = 0; k < 4; ++k) {
    const int tt = t - 3 + k;
    if (tt >= 0) acc = fmaf(xz[(size_t)tt * 1024 + d], wk[k], acc);
  }
  const float s = silu_f(acc);
  xs[idx] = s;
  xs_bf[idx] = f2bf(s);
}

// ---------------------------------------------------------------------------
// Bm = xs @ W_B, Cm = xs @ W_C (f32, tiny N=32)
// ---------------------------------------------------------------------------
__global__ __launch_bounds__(256) void bc_kernel(
    const float* __restrict__ xs, const float* __restrict__ WB,
    const float* __restrict__ WC, float* __restrict__ Bm,
    float* __restrict__ Cm) {
  const int idx = blockIdx.x * 256 + threadIdx.x;
  const int t = idx >> 6;
  const int s = idx & 63;
  const float* __restrict__ W = (s < 32) ? WB : WC;
  const int col = s & 31;
  const float* __restrict__ xr = xs + (size_t)t * D_DIM;
  float acc = 0.f;
#pragma unroll 4
  for (int k = 0; k < D_DIM; k += 4) {
    const float4 xv = *reinterpret_cast<const float4*>(xr + k);
    acc = fmaf(xv.x, W[(k + 0) * 32 + col], acc);
    acc = fmaf(xv.y, W[(k + 1) * 32 + col], acc);
    acc = fmaf(xv.z, W[(k + 2) * 32 + col], acc);
    acc = fmaf(xv.w, W[(k + 3) * 32 + col], acc);
  }
  if (s < 32) Bm[t * 32 + col] = acc;
  else        Cm[t * 32 + col] = acc;
}

// ---------------------------------------------------------------------------
// prep_scan: aT[d][t] = exp(clip(dt*(-exp(log_A[d])))), dtxT[d][t] = dt*xs
// 32x32 tile transpose, coalesced both sides.
// ---------------------------------------------------------------------------
__global__ __launch_bounds__(256) void prep_scan_kernel(
    const float* __restrict__ dt, const float* __restrict__ xs,
    const float* __restrict__ log_A, float* __restrict__ aT,
    float* __restrict__ dtxT) {
  __shared__ float ta[32][33], tx[32][33];
  const int t0 = blockIdx.x * 32;
  const int d0 = blockIdx.y * 32;
  const int i = threadIdx.x & 31;
  const int r = threadIdx.x >> 5;  // 0..7
  const float A = -__expf(log_A[d0 + i]);
#pragma unroll
  for (int p = 0; p < 4; ++p) {
    const int tt = r + p * 8;
    const float dv = dt[(size_t)(t0 + tt) * D_DIM + d0 + i];
    const float xv = xs[(size_t)(t0 + tt) * D_DIM + d0 + i];
    ta[tt][i] = __expf(fminf(fmaxf(dv * A, -20.f), 20.f));
    tx[tt][i] = dv * xv;
  }
  __syncthreads();
#pragma unroll
  for (int p = 0; p < 4; ++p) {
    const int dd = r + p * 8;
    aT[(size_t)(d0 + dd) * T_LEN + t0 + i] = ta[i][dd];
    dtxT[(size_t)(d0 + dd) * T_LEN + t0 + i] = tx[i][dd];
  }
}

// ---------------------------------------------------------------------------
// Chunked SSM scan, single-pass. Block per d; 1024 thr = 32 chunks x 32 s.
// Phase1: local scan, per-t output y_loc and cumulative decay pc (LDS).
// Combine: 32-step chunk-state scan. Phase3 (chain-free): y = y_loc + pc*dot(Hi,C).
// Output yT[d][t] (transposed, contiguous per block).
// ---------------------------------------------------------------------------
__global__ __launch_bounds__(1024) void ssm_scan_kernel(
    const float* __restrict__ aT, const float* __restrict__ dtxT,
    const float* __restrict__ Bm, const float* __restrict__ Cm,
    float* __restrict__ yT) {
  const int d = blockIdx.x;
  const int tid = threadIdx.x;
  const int c = tid >> 5;   // chunk 0..31
  const int s = tid & 31;   // state 0..31
  __shared__ float a_s[2048];
  __shared__ float x_s[2048];
  __shared__ float pc_s[2048];
  __shared__ float yl_s[2048];
  __shared__ float hE[32][32];
  __shared__ float Hi[32][32];

  {
    const float2 va = reinterpret_cast<const float2*>(aT + (size_t)d * T_LEN)[tid];
    const float2 vx = reinterpret_cast<const float2*>(dtxT + (size_t)d * T_LEN)[tid];
    reinterpret_cast<float2*>(a_s)[tid] = va;
    reinterpret_cast<float2*>(x_s)[tid] = vx;
  }
  __syncthreads();

  const int tb = c * 64;
  float h = 0.f, prod = 1.f;
  for (int i = 0; i < 64; ++i) {
    const int t = tb + i;
    const float a = a_s[t];
    h = fmaf(a, h, x_s[t] * Bm[t * 32 + s]);
    prod *= a;
    float p = h * Cm[t * 32 + s];
#pragma unroll
    for (int m = 16; m >= 1; m >>= 1) p += __shfl_xor(p, m);
    if (s == 0) { yl_s[t] = p; pc_s[t] = prod; }
  }
  hE[c][s] = h;
  __syncthreads();

  if (tid < 32) {
    float hh = 0.f;
    for (int cc = 0; cc < 32; ++cc) {
      Hi[cc][tid] = hh;
      hh = fmaf(pc_s[cc * 64 + 63], hh, hE[cc][tid]);
    }
  }
  __syncthreads();

  const float hi = Hi[c][s];
  for (int i = 0; i < 64; ++i) {
    const int t = tb + i;
    float v = hi * Cm[t * 32 + s];
#pragma unroll
    for (int m = 16; m >= 1; m >>= 1) v += __shfl_xor(v, m);
    if (s == 0) yT[(size_t)d * T_LEN + t] = yl_s[t] + pc_s[t] * v;
  }
}

// ---------------------------------------------------------------------------
// gate_tr: g[t,d] = (yT[d,t] + xs*Dp) * silu(z) -> bf16. Tile-transpose of yT.
// ---------------------------------------------------------------------------
__global__ __launch_bounds__(256) void gate_tr_kernel(
    const float* __restrict__ yT, const float* __restrict__ xs,
    const float* __restrict__ Dp, const float* __restrict__ xz,
    unsigned short* __restrict__ g) {
  __shared__ float ty[32][33];
  const int t0 = blockIdx.x * 32;
  const int d0 = blockIdx.y * 32;
  const int i = threadIdx.x & 31;
  const int r = threadIdx.x >> 5;
#pragma unroll
  for (int p = 0; p < 4; ++p) {
    const int dd = r + p * 8;
    ty[dd][i] = yT[(size_t)(d0 + dd) * T_LEN + t0 + i];
  }
  __syncthreads();
  const float dpv = Dp[d0 + i];
#pragma unroll
  for (int p = 0; p < 4; ++p) {
    const int tt = r + p * 8;
    const int t = t0 + tt;
    const int d = d0 + i;
    const float yv = ty[i][tt];
    const float xv = xs[(size_t)t * D_DIM + d];
    const float zv = xz[(size_t)t * 1024 + 512 + d];
    g[(size_t)t * D_DIM + d] = f2bf(fmaf(xv, dpv, yv) * silu_f(zv));
  }
}

__global__ __launch_bounds__(256) void copy_kernel(const float* __restrict__ src,
                                                   float* __restrict__ dst) {
  const int i = blockIdx.x * 256 + threadIdx.x;
  reinterpret_cast<float4*>(dst)[i] = reinterpret_cast<const float4*>(src)[i];
}

// ---------------------------------------------------------------------------
extern "C" void kernel_launch(void* const* d_in, const int* in_sizes, int n_in,
                              void* d_out, int out_size, void* d_ws, size_t ws_size,
                              hipStream_t stream) {
  const float* x      = (const float*)d_in[0];
  const float* norm_w = (const float*)d_in[1];
  const float* W_in   = (const float*)d_in[2];
  const float* conv_w = (const float*)d_in[3];
  const float* conv_b = (const float*)d_in[4];
  const float* W_dt   = (const float*)d_in[5];
  const float* b_dt   = (const float*)d_in[6];
  const float* W_B    = (const float*)d_in[7];
  const float* W_C    = (const float*)d_in[8];
  const float* W_out  = (const float*)d_in[9];
  const float* log_A  = (const float*)d_in[10];
  const float* D_par  = (const float*)d_in[11];
  const float* W_ffn1 = (const float*)d_in[12];
  const float* W_ffn2 = (const float*)d_in[13];
  const float* W_mrg  = (const float*)d_in[14];
  float* out = (float*)d_out;

  const size_t M1 = 1u << 20;  // T*D elements
  char* ws = (char*)d_ws;
  size_t off = 0;
  auto alloc_f = [&](size_t n) { float* p = (float*)(ws + off); off += n * 4; return p; };
  auto alloc_h = [&](size_t n) { unsigned short* p = (unsigned short*)(ws + off); off += n * 2; return p; };

  float* xz   = alloc_f(2 * M1);
  float* xs   = alloc_f(M1);
  float* dt   = alloc_f(M1);
  float* yT   = alloc_f(M1);
  float* aT   = alloc_f(M1);
  float* dtxT = alloc_f(M1);
  float* Bm   = alloc_f(1 << 16);
  float* Cm   = alloc_f(1 << 16);
  unsigned short* xn_bf   = alloc_h(M1);
  unsigned short* xs_bf   = alloc_h(M1);
  unsigned short* g_bf    = alloc_h(M1);
  unsigned short* h1_bf   = alloc_h(2 * M1);
  unsigned short* yssm_bf = alloc_h(M1);
  unsigned short* yffn_bf = alloc_h(M1);
  unsigned short* WinT  = alloc_h(512 * 1024);
  unsigned short* WdtT  = alloc_h(512 * 512);
  unsigned short* WoutT = alloc_h(512 * 512);
  unsigned short* Wf1T  = alloc_h(512 * 1024);
  unsigned short* Wf2T  = alloc_h(512 * 1024);
  unsigned short* Wm1T  = alloc_h(512 * 512);
  unsigned short* Wm2T  = alloc_h(512 * 512);

  // --- weight prep ---
  transpose_bf16_kernel<<<dim3(32, 16), 256, 0, stream>>>(W_in,   WinT, 512, 1024);
  transpose_bf16_kernel<<<dim3(16, 16), 256, 0, stream>>>(W_dt,   WdtT, 512, 512);
  transpose_bf16_kernel<<<dim3(16, 16), 256, 0, stream>>>(W_out,  WoutT, 512, 512);
  transpose_bf16_kernel<<<dim3(32, 16), 256, 0, stream>>>(W_ffn1, Wf1T, 512, 1024);
  transpose_bf16_kernel<<<dim3(16, 32), 256, 0, stream>>>(W_ffn2, Wf2T, 1024, 512);
  transpose_bf16_kernel<<<dim3(16, 16), 256, 0, stream>>>(W_mrg,             Wm1T, 512, 512);
  transpose_bf16_kernel<<<dim3(16, 16), 256, 0, stream>>>(W_mrg + 512 * 512, Wm2T, 512, 512);

  // 1. RMSNorm -> bf16
  rmsnorm_kernel<<<T_LEN, 256, 0, stream>>>(x, norm_w, xn_bf);
  // 2. xz = xn @ W_in  (f32 out)
  gemm_mfma<0, 0, 0><<<dim3(16, 32), 256, 0, stream>>>(xn_bf, WinT, xz, 2048, 1024, 512, nullptr);
  // 3. conv + silu -> xs (f32 + bf16)
  conv_silu_kernel<<<4096, 256, 0, stream>>>(xz, conv_w, conv_b, xs, xs_bf);
  // 4. dt = softplus(xs @ W_dt + b_dt) (f32)
  gemm_mfma<1, 0, 0><<<dim3(8, 32), 256, 0, stream>>>(xs_bf, WdtT, dt, 2048, 512, 512, b_dt);
  // 5. Bm, Cm (f32)
  bc_kernel<<<512, 256, 0, stream>>>(xs, W_B, W_C, Bm, Cm);
  // 6. prep: aT, dtxT  [D,T]
  prep_scan_kernel<<<dim3(64, 16), 256, 0, stream>>>(dt, xs, log_A, aT, dtxT);
  // 7. SSM scan -> yT [D,T]
  ssm_scan_kernel<<<D_DIM, 1024, 0, stream>>>(aT, dtxT, Bm, Cm, yT);
  // 8. gate (+transpose) -> g_bf [T,D]
  gate_tr_kernel<<<dim3(64, 16), 256, 0, stream>>>(yT, xs, D_par, xz, g_bf);
  // 9. y_ssm = g @ W_out -> bf16
  gemm_mfma<0, 1, 0><<<dim3(8, 32), 256, 0, stream>>>(g_bf, WoutT, yssm_bf, 2048, 512, 512, nullptr);
  // 10. h1 = gelu(xn @ W_ffn1) -> bf16
  gemm_mfma<2, 1, 0><<<dim3(16, 32), 256, 0, stream>>>(xn_bf, Wf1T, h1_bf, 2048, 1024, 512, nullptr);
  // 11. y_ffn = h1 @ W_ffn2 -> bf16
  gemm_mfma<0, 1, 0><<<dim3(8, 32), 256, 0, stream>>>(h1_bf, Wf2T, yffn_bf, 2048, 512, 1024, nullptr);
  // 12. out = x + y_ssm @ Wm1 + y_ffn @ Wm2
  copy_kernel<<<1024, 256, 0, stream>>>(x, out);
  gemm_mfma<0, 0, 1><<<dim3(8, 32), 256, 0, stream>>>(yssm_bf, Wm1T, out, 2048, 512, 512, nullptr);
  gemm_mfma<0, 0, 1><<<dim3(8, 32), 256, 0, stream>>>(yffn_bf, Wm2T, out, 2048, 512, 512, nullptr);
}

// Round 4
// 141.888 us; speedup vs baseline: 5.4378x; 1.3959x over previous
//
#include <hip/hip_runtime.h>
#include <math.h>

// Problem constants: B=1, T=2048, D=512, DS=32, EXP=2
#define T_LEN 2048
#define D_DIM 512
#define NCHUNK 64
#define CLEN 32

typedef __bf16 bf16x8 __attribute__((ext_vector_type(8)));
typedef float f32x4 __attribute__((ext_vector_type(4)));

__device__ __forceinline__ float silu_f(float x) { return x / (1.f + __expf(-x)); }
__device__ __forceinline__ float softplus_f(float x) {
  return fmaxf(x, 0.f) + log1pf(__expf(-fabsf(x)));
}
__device__ __forceinline__ float gelu_f(float x) {
  return 0.5f * x * (1.f + erff(x * 0.70710678118654752440f));
}
__device__ __forceinline__ unsigned short f2bf(float f) {
  union { float f; unsigned u; } v; v.f = f;
  unsigned r = v.u + 0x7FFF + ((v.u >> 16) & 1);  // round-nearest-even
  return (unsigned short)(r >> 16);
}

// ---------------------------------------------------------------------------
// RMSNorm -> bf16
// ---------------------------------------------------------------------------
__global__ __launch_bounds__(256) void rmsnorm_kernel(
    const float* __restrict__ x, const float* __restrict__ w,
    unsigned short* __restrict__ xn) {
  const int t = blockIdx.x;
  const float2 v = reinterpret_cast<const float2*>(x + (size_t)t * D_DIM)[threadIdx.x];
  float ss = v.x * v.x + v.y * v.y;
#pragma unroll
  for (int m = 1; m < 64; m <<= 1) ss += __shfl_xor(ss, m);
  __shared__ float wsum[4];
  if ((threadIdx.x & 63) == 0) wsum[threadIdx.x >> 6] = ss;
  __syncthreads();
  const float tot = wsum[0] + wsum[1] + wsum[2] + wsum[3];
  const float scale = rsqrtf(tot * (1.f / D_DIM) + 1e-6f);
  const float2 wv = reinterpret_cast<const float2*>(w)[threadIdx.x];
  ushort2 o;
  o.x = f2bf(v.x * scale * wv.x);
  o.y = f2bf(v.y * scale * wv.y);
  reinterpret_cast<ushort2*>(xn + (size_t)t * D_DIM)[threadIdx.x] = o;
}

// ---------------------------------------------------------------------------
// Weight transpose + f32->bf16: src f32 [K,N] -> dst bf16 [N,K]
// ---------------------------------------------------------------------------
__global__ __launch_bounds__(256) void transpose_bf16_kernel(
    const float* __restrict__ src, unsigned short* __restrict__ dst,
    int K, int N) {
  __shared__ float tile[32][33];
  const int k0 = blockIdx.y * 32, n0 = blockIdx.x * 32;
  const int i = threadIdx.x & 31;
  const int r = threadIdx.x >> 5;
#pragma unroll
  for (int p = 0; p < 4; ++p) {
    const int kk = r + p * 8;
    tile[kk][i] = src[(size_t)(k0 + kk) * N + n0 + i];
  }
  __syncthreads();
#pragma unroll
  for (int p = 0; p < 4; ++p) {
    const int nn = r + p * 8;
    dst[(size_t)(n0 + nn) * K + k0 + i] = f2bf(tile[i][nn]);
  }
}

// ---------------------------------------------------------------------------
// bf16 MFMA GEMM (64x64 tile, BK=64, XOR-swizzled LDS)
// ---------------------------------------------------------------------------
template <int ACT, int OUTBF, int ACC>
__global__ __launch_bounds__(256) void gemm_mfma(
    const unsigned short* __restrict__ Abf, const unsigned short* __restrict__ Btbf,
    void* __restrict__ Cout, int M, int N, int K,
    const float* __restrict__ bias) {
  __shared__ bf16x8 As[512];
  __shared__ bf16x8 Bs[512];

  const int tid = threadIdx.x;
  const int lane = tid & 63;
  const int w = tid >> 6;
  const int wrow = (w >> 1) * 32;
  const int wcol = (w & 1) * 32;
  const int brow = blockIdx.y * 64;
  const int bcol = blockIdx.x * 64;
  const int K8 = K >> 3;

  const bf16x8* __restrict__ A8 = reinterpret_cast<const bf16x8*>(Abf);
  const bf16x8* __restrict__ B8 = reinterpret_cast<const bf16x8*>(Btbf);

  const int r0s = tid >> 3;
  const int c0s = tid & 7;

  f32x4 acc[2][2];
#pragma unroll
  for (int m = 0; m < 2; ++m)
#pragma unroll
    for (int n = 0; n < 2; ++n) acc[m][n] = {0.f, 0.f, 0.f, 0.f};

  const int nt = K >> 6;
  bf16x8 pa[2], pb[2];
#pragma unroll
  for (int p = 0; p < 2; ++p) {
    const int rr = r0s + p * 32;
    pa[p] = A8[(size_t)(brow + rr) * K8 + c0s];
    pb[p] = B8[(size_t)(bcol + rr) * K8 + c0s];
  }

  for (int t = 0; t < nt; ++t) {
#pragma unroll
    for (int p = 0; p < 2; ++p) {
      const int rr = r0s + p * 32;
      As[rr * 8 + (c0s ^ (rr & 7))] = pa[p];
      Bs[rr * 8 + (c0s ^ (rr & 7))] = pb[p];
    }
    __syncthreads();
    if (t + 1 < nt) {
      const int kb = (t + 1) * 8;
#pragma unroll
      for (int p = 0; p < 2; ++p) {
        const int rr = r0s + p * 32;
        pa[p] = A8[(size_t)(brow + rr) * K8 + kb + c0s];
        pb[p] = B8[(size_t)(bcol + rr) * K8 + kb + c0s];
      }
    }
#pragma unroll
    for (int kk = 0; kk < 2; ++kk) {
      const int slot = kk * 4 + (lane >> 4);
      bf16x8 af[2], bf_[2];
#pragma unroll
      for (int m = 0; m < 2; ++m) {
        const int r = wrow + m * 16 + (lane & 15);
        af[m] = As[r * 8 + (slot ^ (r & 7))];
      }
#pragma unroll
      for (int n = 0; n < 2; ++n) {
        const int r = wcol + n * 16 + (lane & 15);
        bf_[n] = Bs[r * 8 + (slot ^ (r & 7))];
      }
#pragma unroll
      for (int m = 0; m < 2; ++m)
#pragma unroll
        for (int n = 0; n < 2; ++n)
          acc[m][n] = __builtin_amdgcn_mfma_f32_16x16x32_bf16(af[m], bf_[n], acc[m][n], 0, 0, 0);
    }
    __syncthreads();
  }

#pragma unroll
  for (int m = 0; m < 2; ++m) {
#pragma unroll
    for (int n = 0; n < 2; ++n) {
      const int col = bcol + wcol + n * 16 + (lane & 15);
      const float bv = bias ? bias[col] : 0.f;
#pragma unroll
      for (int j = 0; j < 4; ++j) {
        const int row = brow + wrow + m * 16 + (lane >> 4) * 4 + j;
        float v = acc[m][n][j] + bv;
        if (ACT == 1) v = softplus_f(v);
        else if (ACT == 2) v = gelu_f(v);
        if (OUTBF) {
          reinterpret_cast<unsigned short*>(Cout)[(size_t)row * N + col] = f2bf(v);
        } else {
          float* cp = reinterpret_cast<float*>(Cout) + (size_t)row * N + col;
          if (ACC) v += *cp;
          *cp = v;
        }
      }
    }
  }
}

// ---------------------------------------------------------------------------
// Causal depthwise conv (k=4) + bias + SiLU -> f32 + bf16
// ---------------------------------------------------------------------------
__global__ __launch_bounds__(256) void conv_silu_kernel(
    const float* __restrict__ xz, const float* __restrict__ cw,
    const float* __restrict__ cb, float* __restrict__ xs,
    unsigned short* __restrict__ xs_bf) {
  const int idx = blockIdx.x * 256 + threadIdx.x;
  const int t = idx >> 9;
  const int d = idx & 511;
  const float4 w = reinterpret_cast<const float4*>(cw)[d];
  float acc = cb[d];
  const float wk[4] = {w.x, w.y, w.z, w.w};
#pragma unroll
  for (int k = 0; k < 4; ++k) {
    const int tt = t - 3 + k;
    if (tt >= 0) acc = fmaf(xz[(size_t)tt * 1024 + d], wk[k], acc);
  }
  const float s = silu_f(acc);
  xs[idx] = s;
  xs_bf[idx] = f2bf(s);
}

// ---------------------------------------------------------------------------
// Bm = xs @ W_B, Cm = xs @ W_C (f32)
// ---------------------------------------------------------------------------
__global__ __launch_bounds__(256) void bc_kernel(
    const float* __restrict__ xs, const float* __restrict__ WB,
    const float* __restrict__ WC, float* __restrict__ Bm,
    float* __restrict__ Cm) {
  const int idx = blockIdx.x * 256 + threadIdx.x;
  const int t = idx >> 6;
  const int s = idx & 63;
  const float* __restrict__ W = (s < 32) ? WB : WC;
  const int col = s & 31;
  const float* __restrict__ xr = xs + (size_t)t * D_DIM;
  float acc = 0.f;
#pragma unroll 4
  for (int k = 0; k < D_DIM; k += 4) {
    const float4 xv = *reinterpret_cast<const float4*>(xr + k);
    acc = fmaf(xv.x, W[(k + 0) * 32 + col], acc);
    acc = fmaf(xv.y, W[(k + 1) * 32 + col], acc);
    acc = fmaf(xv.z, W[(k + 2) * 32 + col], acc);
    acc = fmaf(xv.w, W[(k + 3) * 32 + col], acc);
  }
  if (s < 32) Bm[t * 32 + col] = acc;
  else        Cm[t * 32 + col] = acc;
}

// ---------------------------------------------------------------------------
// S1 chunk prep: per chunk c (L=32), per d:
//   cum[t] = sum clip(dt*A);  E[t,d]=exp(cum);  u=exp(-cum)*dt*xs
//   U_T[d][c*32+t] = bf16(u);  V[c][d][s] = sum_t u*B[t,s];  Pc[c][d]=exp(cum_end)
// grid (64 chunks, 2 dgroups) x 256 threads (one per d)
// ---------------------------------------------------------------------------
__global__ __launch_bounds__(256) void chunk_prep_kernel(
    const float* __restrict__ dt, const float* __restrict__ xs,
    const float* __restrict__ Bm, const float* __restrict__ log_A,
    unsigned short* __restrict__ U_T, float* __restrict__ E,
    float* __restrict__ V, float* __restrict__ Pc) {
  const int c = blockIdx.x;
  const int d = blockIdx.y * 256 + threadIdx.x;
  __shared__ float4 Bls[CLEN * 8];  // [t][s/4]
  Bls[threadIdx.x] = reinterpret_cast<const float4*>(Bm + c * CLEN * 32)[threadIdx.x];
  __syncthreads();

  const float A = -__expf(log_A[d]);
  float cum = 0.f;
  float e = 1.f;
  float vacc[32];
#pragma unroll
  for (int s = 0; s < 32; ++s) vacc[s] = 0.f;
  unsigned pk[16];
#pragma unroll
  for (int t = 0; t < CLEN; ++t) {
    const int tg = c * CLEN + t;
    const float dtv = dt[(size_t)tg * D_DIM + d];
    const float xv  = xs[(size_t)tg * D_DIM + d];
    const float la = fminf(fmaxf(dtv * A, -20.f), 20.f);
    cum += la;
    e = __expf(cum);
    E[(size_t)tg * D_DIM + d] = e;
    const float u = __expf(-cum) * dtv * xv;
    const unsigned short ub = f2bf(u);
    if ((t & 1) == 0) pk[t >> 1] = (unsigned)ub;
    else              pk[t >> 1] |= ((unsigned)ub) << 16;
#pragma unroll
    for (int s4 = 0; s4 < 8; ++s4) {
      const float4 b = Bls[t * 8 + s4];
      vacc[s4 * 4 + 0] = fmaf(u, b.x, vacc[s4 * 4 + 0]);
      vacc[s4 * 4 + 1] = fmaf(u, b.y, vacc[s4 * 4 + 1]);
      vacc[s4 * 4 + 2] = fmaf(u, b.z, vacc[s4 * 4 + 2]);
      vacc[s4 * 4 + 3] = fmaf(u, b.w, vacc[s4 * 4 + 3]);
    }
  }
  {
    uint4* dst = reinterpret_cast<uint4*>(U_T + (size_t)d * T_LEN + c * CLEN);
    dst[0] = make_uint4(pk[0], pk[1], pk[2], pk[3]);
    dst[1] = make_uint4(pk[4], pk[5], pk[6], pk[7]);
    dst[2] = make_uint4(pk[8], pk[9], pk[10], pk[11]);
    dst[3] = make_uint4(pk[12], pk[13], pk[14], pk[15]);
  }
  {
    float4* dst = reinterpret_cast<float4*>(V + ((size_t)c * D_DIM + d) * 32);
#pragma unroll
    for (int s4 = 0; s4 < 8; ++s4)
      dst[s4] = make_float4(vacc[s4 * 4], vacc[s4 * 4 + 1], vacc[s4 * 4 + 2], vacc[s4 * 4 + 3]);
  }
  Pc[c * D_DIM + d] = e;
}

// ---------------------------------------------------------------------------
// Gram: Gm[c][t][t'] = (t'<=t) ? sum_s C[c,t,s]*B[c,t',s] : 0   (bf16)
// ---------------------------------------------------------------------------
__global__ __launch_bounds__(256) void gram_kernel(
    const float* __restrict__ Bm, const float* __restrict__ Cm,
    unsigned short* __restrict__ Gm) {
  const int c = blockIdx.x;
  __shared__ float Bls[32][33], Cls[32][33];
  {
    const int t = threadIdx.x >> 3;
    const int s4 = threadIdx.x & 7;
    const float4 b = reinterpret_cast<const float4*>(Bm + (c * CLEN + t) * 32)[s4];
    const float4 cc = reinterpret_cast<const float4*>(Cm + (c * CLEN + t) * 32)[s4];
    Bls[t][s4 * 4 + 0] = b.x;  Bls[t][s4 * 4 + 1] = b.y;
    Bls[t][s4 * 4 + 2] = b.z;  Bls[t][s4 * 4 + 3] = b.w;
    Cls[t][s4 * 4 + 0] = cc.x; Cls[t][s4 * 4 + 1] = cc.y;
    Cls[t][s4 * 4 + 2] = cc.z; Cls[t][s4 * 4 + 3] = cc.w;
  }
  __syncthreads();
  const int t = threadIdx.x >> 3;
  const int tp0 = (threadIdx.x & 7) * 4;
  float g[4];
#pragma unroll
  for (int q = 0; q < 4; ++q) {
    const int tp = tp0 + q;
    float acc = 0.f;
    if (tp <= t) {
#pragma unroll
      for (int s = 0; s < 32; ++s) acc = fmaf(Cls[t][s], Bls[tp][s], acc);
    }
    g[q] = acc;
  }
  ushort4 o;
  o.x = f2bf(g[0]); o.y = f2bf(g[1]); o.z = f2bf(g[2]); o.w = f2bf(g[3]);
  reinterpret_cast<ushort4*>(Gm + c * 1024)[threadIdx.x] = o;
}

// ---------------------------------------------------------------------------
// S2 state scan: Hin[c][d][s]; h_{c+1} = Pc[c][d]*(h_c + V[c][d][s])
// 16384 threads, coalesced, 64 serial steps.
// ---------------------------------------------------------------------------
__global__ __launch_bounds__(256) void state_scan_kernel(
    const float* __restrict__ V, const float* __restrict__ Pc,
    float* __restrict__ Hin) {
  const int gt = blockIdx.x * 256 + threadIdx.x;  // d*32+s
  const int d = gt >> 5;
  float h = 0.f;
  for (int c = 0; c < NCHUNK; ++c) {
    Hin[c * 16384 + gt] = h;
    h = Pc[c * D_DIM + d] * (h + V[c * 16384 + gt]);
  }
}

// ---------------------------------------------------------------------------
// S3: per (chunk c, dtile): out[32t x 64d] = [Gm|C_c] @ [U_T ; Hin]^T-style
//   y[t,d] = E[t,d] * acc;  g = (y + xs*Dp)*silu(z) -> bf16  (gate fused)
// A rows t (K: t'<32 then s<32), B rows d.
// ---------------------------------------------------------------------------
__global__ __launch_bounds__(256) void ssm_out_kernel(
    const unsigned short* __restrict__ Gm, const unsigned short* __restrict__ U_T,
    const float* __restrict__ Hin, const float* __restrict__ Cm,
    const float* __restrict__ E, const float* __restrict__ xs,
    const float* __restrict__ Dp, const float* __restrict__ xz,
    unsigned short* __restrict__ g) {
  const int c = blockIdx.x;
  const int dt0 = blockIdx.y * 64;
  __shared__ bf16x8 Als[32 * 8];
  __shared__ bf16x8 Bls[64 * 8];
  const int tid = threadIdx.x;

  // A stage: rows t (32), slots 0..3 = Gm row, slots 4..7 = C chunk (f32->bf16)
  if (tid < 128) {
    const int t = tid >> 2, q = tid & 3;
    Als[t * 8 + (q ^ (t & 7))] =
        *reinterpret_cast<const bf16x8*>(Gm + c * 1024 + t * 32 + q * 8);
  } else {
    const int i = tid - 128;
    const int t = i >> 2, q = i & 3;
    const float* cp = Cm + (c * CLEN + t) * 32 + q * 8;
    const float4 c0 = *reinterpret_cast<const float4*>(cp);
    const float4 c1 = *reinterpret_cast<const float4*>(cp + 4);
    union { bf16x8 v; unsigned short u[8]; } wv;
    wv.u[0] = f2bf(c0.x); wv.u[1] = f2bf(c0.y); wv.u[2] = f2bf(c0.z); wv.u[3] = f2bf(c0.w);
    wv.u[4] = f2bf(c1.x); wv.u[5] = f2bf(c1.y); wv.u[6] = f2bf(c1.z); wv.u[7] = f2bf(c1.w);
    Als[t * 8 + ((4 + q) ^ (t & 7))] = wv.v;
  }
  // B stage: rows d (64), slots 0..3 = U_T slice, slots 4..7 = Hin (f32->bf16)
  {
    const int dd = tid >> 2, q = tid & 3;
    Bls[dd * 8 + (q ^ (dd & 7))] = *reinterpret_cast<const bf16x8*>(
        U_T + (size_t)(dt0 + dd) * T_LEN + c * CLEN + q * 8);
    const float* hp = Hin + ((size_t)c * D_DIM + dt0 + dd) * 32 + q * 8;
    const float4 h0 = *reinterpret_cast<const float4*>(hp);
    const float4 h1 = *reinterpret_cast<const float4*>(hp + 4);
    union { bf16x8 v; unsigned short u[8]; } wv;
    wv.u[0] = f2bf(h0.x); wv.u[1] = f2bf(h0.y); wv.u[2] = f2bf(h0.z); wv.u[3] = f2bf(h0.w);
    wv.u[4] = f2bf(h1.x); wv.u[5] = f2bf(h1.y); wv.u[6] = f2bf(h1.z); wv.u[7] = f2bf(h1.w);
    Bls[dd * 8 + ((4 + q) ^ (dd & 7))] = wv.v;
  }
  __syncthreads();

  const int lane = tid & 63;
  const int w = tid >> 6;
  const int wcol = w * 16;  // d-offset of this wave
  f32x4 acc[2];
  acc[0] = {0.f, 0.f, 0.f, 0.f};
  acc[1] = {0.f, 0.f, 0.f, 0.f};
#pragma unroll
  for (int kk = 0; kk < 2; ++kk) {
    const int slot = kk * 4 + (lane >> 4);
    const int rb = wcol + (lane & 15);
    const bf16x8 bfrag = Bls[rb * 8 + (slot ^ (rb & 7))];
#pragma unroll
    for (int m = 0; m < 2; ++m) {
      const int r = m * 16 + (lane & 15);
      const bf16x8 afrag = Als[r * 8 + (slot ^ (r & 7))];
      acc[m] = __builtin_amdgcn_mfma_f32_16x16x32_bf16(afrag, bfrag, acc[m], 0, 0, 0);
    }
  }
  const int dg = dt0 + wcol + (lane & 15);
  const float dpv = Dp[dg];
#pragma unroll
  for (int m = 0; m < 2; ++m) {
#pragma unroll
    for (int j = 0; j < 4; ++j) {
      const int tg = c * CLEN + m * 16 + (lane >> 4) * 4 + j;
      const float y = E[(size_t)tg * D_DIM + dg] * acc[m][j];
      const float xv = xs[(size_t)tg * D_DIM + dg];
      const float zv = xz[(size_t)tg * 1024 + 512 + dg];
      g[(size_t)tg * D_DIM + dg] = f2bf(fmaf(xv, dpv, y) * silu_f(zv));
    }
  }
}

__global__ __launch_bounds__(256) void copy_kernel(const float* __restrict__ src,
                                                   float* __restrict__ dst) {
  const int i = blockIdx.x * 256 + threadIdx.x;
  reinterpret_cast<float4*>(dst)[i] = reinterpret_cast<const float4*>(src)[i];
}

// ---------------------------------------------------------------------------
extern "C" void kernel_launch(void* const* d_in, const int* in_sizes, int n_in,
                              void* d_out, int out_size, void* d_ws, size_t ws_size,
                              hipStream_t stream) {
  const float* x      = (const float*)d_in[0];
  const float* norm_w = (const float*)d_in[1];
  const float* W_in   = (const float*)d_in[2];
  const float* conv_w = (const float*)d_in[3];
  const float* conv_b = (const float*)d_in[4];
  const float* W_dt   = (const float*)d_in[5];
  const float* b_dt   = (const float*)d_in[6];
  const float* W_B    = (const float*)d_in[7];
  const float* W_C    = (const float*)d_in[8];
  const float* W_out  = (const float*)d_in[9];
  const float* log_A  = (const float*)d_in[10];
  const float* D_par  = (const float*)d_in[11];
  const float* W_ffn1 = (const float*)d_in[12];
  const float* W_ffn2 = (const float*)d_in[13];
  const float* W_mrg  = (const float*)d_in[14];
  float* out = (float*)d_out;

  const size_t M1 = 1u << 20;
  char* ws = (char*)d_ws;
  size_t off = 0;
  auto alloc_f = [&](size_t n) { float* p = (float*)(ws + off); off += n * 4; return p; };
  auto alloc_h = [&](size_t n) { unsigned short* p = (unsigned short*)(ws + off); off += n * 2; return p; };

  float* xz  = alloc_f(2 * M1);
  float* xs  = alloc_f(M1);
  float* dt  = alloc_f(M1);
  float* E   = alloc_f(M1);
  float* V   = alloc_f(M1);       // [64][512][32]
  float* Hin = alloc_f(M1);       // [64][512][32]
  float* Bm  = alloc_f(1 << 16);
  float* Cm  = alloc_f(1 << 16);
  float* Pc  = alloc_f(NCHUNK * D_DIM);
  unsigned short* U_T     = alloc_h(M1);       // [512][2048]
  unsigned short* Gm      = alloc_h(NCHUNK * 1024);
  unsigned short* xn_bf   = alloc_h(M1);
  unsigned short* xs_bf   = alloc_h(M1);
  unsigned short* g_bf    = alloc_h(M1);
  unsigned short* h1_bf   = alloc_h(2 * M1);
  unsigned short* yssm_bf = alloc_h(M1);
  unsigned short* yffn_bf = alloc_h(M1);
  unsigned short* WinT  = alloc_h(512 * 1024);
  unsigned short* WdtT  = alloc_h(512 * 512);
  unsigned short* WoutT = alloc_h(512 * 512);
  unsigned short* Wf1T  = alloc_h(512 * 1024);
  unsigned short* Wf2T  = alloc_h(512 * 1024);
  unsigned short* Wm1T  = alloc_h(512 * 512);
  unsigned short* Wm2T  = alloc_h(512 * 512);

  // --- weight prep ---
  transpose_bf16_kernel<<<dim3(32, 16), 256, 0, stream>>>(W_in,   WinT, 512, 1024);
  transpose_bf16_kernel<<<dim3(16, 16), 256, 0, stream>>>(W_dt,   WdtT, 512, 512);
  transpose_bf16_kernel<<<dim3(16, 16), 256, 0, stream>>>(W_out,  WoutT, 512, 512);
  transpose_bf16_kernel<<<dim3(32, 16), 256, 0, stream>>>(W_ffn1, Wf1T, 512, 1024);
  transpose_bf16_kernel<<<dim3(16, 32), 256, 0, stream>>>(W_ffn2, Wf2T, 1024, 512);
  transpose_bf16_kernel<<<dim3(16, 16), 256, 0, stream>>>(W_mrg,             Wm1T, 512, 512);
  transpose_bf16_kernel<<<dim3(16, 16), 256, 0, stream>>>(W_mrg + 512 * 512, Wm2T, 512, 512);

  // 1. RMSNorm -> bf16
  rmsnorm_kernel<<<T_LEN, 256, 0, stream>>>(x, norm_w, xn_bf);
  // 2. xz = xn @ W_in
  gemm_mfma<0, 0, 0><<<dim3(16, 32), 256, 0, stream>>>(xn_bf, WinT, xz, 2048, 1024, 512, nullptr);
  // 3. conv + silu
  conv_silu_kernel<<<4096, 256, 0, stream>>>(xz, conv_w, conv_b, xs, xs_bf);
  // 4. dt = softplus(xs @ W_dt + b_dt)
  gemm_mfma<1, 0, 0><<<dim3(8, 32), 256, 0, stream>>>(xs_bf, WdtT, dt, 2048, 512, 512, b_dt);
  // 5. Bm, Cm
  bc_kernel<<<512, 256, 0, stream>>>(xs, W_B, W_C, Bm, Cm);
  // 6. chunk prep (S1)
  chunk_prep_kernel<<<dim3(NCHUNK, 2), 256, 0, stream>>>(dt, xs, Bm, log_A, U_T, E, V, Pc);
  // 7. gram matrices
  gram_kernel<<<NCHUNK, 256, 0, stream>>>(Bm, Cm, Gm);
  // 8. inter-chunk state scan (S2)
  state_scan_kernel<<<64, 256, 0, stream>>>(V, Pc, Hin);
  // 9. intra+inter output + fused gate (S3) -> g_bf
  ssm_out_kernel<<<dim3(NCHUNK, 8), 256, 0, stream>>>(Gm, U_T, Hin, Cm, E, xs, D_par, xz, g_bf);
  // 10. y_ssm = g @ W_out -> bf16
  gemm_mfma<0, 1, 0><<<dim3(8, 32), 256, 0, stream>>>(g_bf, WoutT, yssm_bf, 2048, 512, 512, nullptr);
  // 11. h1 = gelu(xn @ W_ffn1) -> bf16
  gemm_mfma<2, 1, 0><<<dim3(16, 32), 256, 0, stream>>>(xn_bf, Wf1T, h1_bf, 2048, 1024, 512, nullptr);
  // 12. y_ffn = h1 @ W_ffn2 -> bf16
  gemm_mfma<0, 1, 0><<<dim3(8, 32), 256, 0, stream>>>(h1_bf, Wf2T, yffn_bf, 2048, 512, 1024, nullptr);
  // 13. out = x + y_ssm @ Wm1 + y_ffn @ Wm2
  copy_kernel<<<1024, 256, 0, stream>>>(x, out);
  gemm_mfma<0, 0, 1><<<dim3(8, 32), 256, 0, stream>>>(yssm_bf, Wm1T, out, 2048, 512, 512, nullptr);
  gemm_mfma<0, 0, 1><<<dim3(8, 32), 256, 0, stream>>>(yffn_bf, Wm2T, out, 2048, 512, 512, nullptr);
}

// Round 5
// 116.232 us; speedup vs baseline: 6.6381x; 1.2207x over previous
//
#include <hip/hip_runtime.h>
#include <math.h>

// Problem constants: B=1, T=2048, D=512, DS=32, EXP=2
#define T_LEN 2048
#define D_DIM 512
#define NCHUNK 64
#define CLEN 32

typedef __bf16 bf16x8 __attribute__((ext_vector_type(8)));
typedef float f32x4 __attribute__((ext_vector_type(4)));

__device__ __forceinline__ float silu_f(float x) { return x / (1.f + __expf(-x)); }
__device__ __forceinline__ float softplus_f(float x) {
  return fmaxf(x, 0.f) + log1pf(__expf(-fabsf(x)));
}
__device__ __forceinline__ float gelu_f(float x) {
  return 0.5f * x * (1.f + erff(x * 0.70710678118654752440f));
}
__device__ __forceinline__ unsigned short f2bf(float f) {
  union { float f; unsigned u; } v; v.f = f;
  unsigned r = v.u + 0x7FFF + ((v.u >> 16) & 1);  // round-nearest-even
  return (unsigned short)(r >> 16);
}

// ---------------------------------------------------------------------------
// RMSNorm -> bf16
// ---------------------------------------------------------------------------
__global__ __launch_bounds__(256) void rmsnorm_kernel(
    const float* __restrict__ x, const float* __restrict__ w,
    unsigned short* __restrict__ xn) {
  const int t = blockIdx.x;
  const float2 v = reinterpret_cast<const float2*>(x + (size_t)t * D_DIM)[threadIdx.x];
  float ss = v.x * v.x + v.y * v.y;
#pragma unroll
  for (int m = 1; m < 64; m <<= 1) ss += __shfl_xor(ss, m);
  __shared__ float wsum[4];
  if ((threadIdx.x & 63) == 0) wsum[threadIdx.x >> 6] = ss;
  __syncthreads();
  const float tot = wsum[0] + wsum[1] + wsum[2] + wsum[3];
  const float scale = rsqrtf(tot * (1.f / D_DIM) + 1e-6f);
  const float2 wv = reinterpret_cast<const float2*>(w)[threadIdx.x];
  ushort2 o;
  o.x = f2bf(v.x * scale * wv.x);
  o.y = f2bf(v.y * scale * wv.y);
  reinterpret_cast<ushort2*>(xn + (size_t)t * D_DIM)[threadIdx.x] = o;
}

// ---------------------------------------------------------------------------
// Weight transpose + f32->bf16: src f32 [K,N] -> dst bf16 [N,K] (ld = K)
// ---------------------------------------------------------------------------
__global__ __launch_bounds__(256) void transpose_bf16_kernel(
    const float* __restrict__ src, unsigned short* __restrict__ dst,
    int K, int N) {
  __shared__ float tile[32][33];
  const int k0 = blockIdx.y * 32, n0 = blockIdx.x * 32;
  const int i = threadIdx.x & 31;
  const int r = threadIdx.x >> 5;
#pragma unroll
  for (int p = 0; p < 4; ++p) {
    const int kk = r + p * 8;
    tile[kk][i] = src[(size_t)(k0 + kk) * N + n0 + i];
  }
  __syncthreads();
#pragma unroll
  for (int p = 0; p < 4; ++p) {
    const int nn = r + p * 8;
    dst[(size_t)(n0 + nn) * K + k0 + i] = f2bf(tile[i][nn]);
  }
}

// ---------------------------------------------------------------------------
// bf16 MFMA GEMM (64x64 tile, BK=64, XOR-swizzled LDS, reg-staged prefetch)
// MODE 0 (INF1):  N=2048; col<1024 -> f32 O1[row*1024+col]; else gelu->bf16
//                 O2[row*1024+col-1024]
// MODE 1 (DTBC):  N=576; col<512 -> softplus(v+bias[col]) f32 O1[row*512+col];
//                 col 512..543 -> f32 O2[row*32+s]; 544..575 -> f32 O3[row*32+s]
// MODE 2 (BF16LD): bf16 O1[row*ldC+col]
// MODE 3 (MERGE): f32 O1[row*512+col] = resid[row*512+col] + v
// ---------------------------------------------------------------------------
template <int MODE>
__global__ __launch_bounds__(256) void gemm_mfma(
    const unsigned short* __restrict__ Abf, const unsigned short* __restrict__ Btbf,
    void* __restrict__ O1, void* __restrict__ O2, void* __restrict__ O3,
    int M, int N, int K, int ldC,
    const float* __restrict__ bias, const float* __restrict__ resid) {
  __shared__ bf16x8 As[512];
  __shared__ bf16x8 Bs[512];

  const int tid = threadIdx.x;
  const int lane = tid & 63;
  const int w = tid >> 6;
  const int wrow = (w >> 1) * 32;
  const int wcol = (w & 1) * 32;
  const int brow = blockIdx.y * 64;
  const int bcol = blockIdx.x * 64;
  const int K8 = K >> 3;

  const bf16x8* __restrict__ A8 = reinterpret_cast<const bf16x8*>(Abf);
  const bf16x8* __restrict__ B8 = reinterpret_cast<const bf16x8*>(Btbf);

  const int r0s = tid >> 3;
  const int c0s = tid & 7;

  f32x4 acc[2][2];
#pragma unroll
  for (int m = 0; m < 2; ++m)
#pragma unroll
    for (int n = 0; n < 2; ++n) acc[m][n] = {0.f, 0.f, 0.f, 0.f};

  const int nt = K >> 6;
  bf16x8 pa[2], pb[2];
#pragma unroll
  for (int p = 0; p < 2; ++p) {
    const int rr = r0s + p * 32;
    pa[p] = A8[(size_t)(brow + rr) * K8 + c0s];
    pb[p] = B8[(size_t)(bcol + rr) * K8 + c0s];
  }

  for (int t = 0; t < nt; ++t) {
#pragma unroll
    for (int p = 0; p < 2; ++p) {
      const int rr = r0s + p * 32;
      As[rr * 8 + (c0s ^ (rr & 7))] = pa[p];
      Bs[rr * 8 + (c0s ^ (rr & 7))] = pb[p];
    }
    __syncthreads();
    if (t + 1 < nt) {
      const int kb = (t + 1) * 8;
#pragma unroll
      for (int p = 0; p < 2; ++p) {
        const int rr = r0s + p * 32;
        pa[p] = A8[(size_t)(brow + rr) * K8 + kb + c0s];
        pb[p] = B8[(size_t)(bcol + rr) * K8 + kb + c0s];
      }
    }
#pragma unroll
    for (int kk = 0; kk < 2; ++kk) {
      const int slot = kk * 4 + (lane >> 4);
      bf16x8 af[2], bf_[2];
#pragma unroll
      for (int m = 0; m < 2; ++m) {
        const int r = wrow + m * 16 + (lane & 15);
        af[m] = As[r * 8 + (slot ^ (r & 7))];
      }
#pragma unroll
      for (int n = 0; n < 2; ++n) {
        const int r = wcol + n * 16 + (lane & 15);
        bf_[n] = Bs[r * 8 + (slot ^ (r & 7))];
      }
#pragma unroll
      for (int m = 0; m < 2; ++m)
#pragma unroll
        for (int n = 0; n < 2; ++n)
          acc[m][n] = __builtin_amdgcn_mfma_f32_16x16x32_bf16(af[m], bf_[n], acc[m][n], 0, 0, 0);
    }
    __syncthreads();
  }

#pragma unroll
  for (int m = 0; m < 2; ++m) {
#pragma unroll
    for (int n = 0; n < 2; ++n) {
      const int col = bcol + wcol + n * 16 + (lane & 15);
#pragma unroll
      for (int j = 0; j < 4; ++j) {
        const int row = brow + wrow + m * 16 + (lane >> 4) * 4 + j;
        float v = acc[m][n][j];
        if (MODE == 0) {
          if (col < 1024) {
            reinterpret_cast<float*>(O1)[(size_t)row * 1024 + col] = v;
          } else {
            reinterpret_cast<unsigned short*>(O2)[(size_t)row * 1024 + col - 1024] =
                f2bf(gelu_f(v));
          }
        } else if (MODE == 1) {
          if (col < 512) {
            reinterpret_cast<float*>(O1)[(size_t)row * 512 + col] =
                softplus_f(v + bias[col]);
          } else {
            const int s = col - 512;
            float* p = (s < 32) ? reinterpret_cast<float*>(O2)
                                : reinterpret_cast<float*>(O3);
            p[(size_t)row * 32 + (s & 31)] = v;
          }
        } else if (MODE == 2) {
          reinterpret_cast<unsigned short*>(O1)[(size_t)row * ldC + col] = f2bf(v);
        } else {  // MODE 3
          reinterpret_cast<float*>(O1)[(size_t)row * 512 + col] =
              resid[(size_t)row * 512 + col] + v;
        }
      }
    }
  }
}

// ---------------------------------------------------------------------------
// Causal depthwise conv (k=4) + bias + SiLU -> f32 + bf16
// ---------------------------------------------------------------------------
__global__ __launch_bounds__(256) void conv_silu_kernel(
    const float* __restrict__ xz, const float* __restrict__ cw,
    const float* __restrict__ cb, float* __restrict__ xs,
    unsigned short* __restrict__ xs_bf) {
  const int idx = blockIdx.x * 256 + threadIdx.x;
  const int t = idx >> 9;
  const int d = idx & 511;
  const float4 w = reinterpret_cast<const float4*>(cw)[d];
  float acc = cb[d];
  const float wk[4] = {w.x, w.y, w.z, w.w};
#pragma unroll
  for (int k = 0; k < 4; ++k) {
    const int tt = t - 3 + k;
    if (tt >= 0) acc = fmaf(xz[(size_t)tt * 1024 + d], wk[k], acc);
  }
  const float s = silu_f(acc);
  xs[idx] = s;
  xs_bf[idx] = f2bf(s);
}

// ---------------------------------------------------------------------------
// S1 chunk prep: per chunk c (L=32), per d:
//   cum[t] = sum clip(dt*A);  E[t,d]=exp(cum);  u=exp(-cum)*dt*xs
//   U_T[d][c*32+t] = bf16(u);  V[c][d][s] = sum_t u*B[t,s];  Pc[c][d]=exp(cum_end)
// ---------------------------------------------------------------------------
__global__ __launch_bounds__(256) void chunk_prep_kernel(
    const float* __restrict__ dt, const float* __restrict__ xs,
    const float* __restrict__ Bm, const float* __restrict__ log_A,
    unsigned short* __restrict__ U_T, float* __restrict__ E,
    float* __restrict__ V, float* __restrict__ Pc) {
  const int c = blockIdx.x;
  const int d = blockIdx.y * 256 + threadIdx.x;
  __shared__ float4 Bls[CLEN * 8];  // [t][s/4]
  Bls[threadIdx.x] = reinterpret_cast<const float4*>(Bm + c * CLEN * 32)[threadIdx.x];
  __syncthreads();

  const float A = -__expf(log_A[d]);
  float cum = 0.f;
  float e = 1.f;
  float vacc[32];
#pragma unroll
  for (int s = 0; s < 32; ++s) vacc[s] = 0.f;
  unsigned pk[16];
#pragma unroll
  for (int t = 0; t < CLEN; ++t) {
    const int tg = c * CLEN + t;
    const float dtv = dt[(size_t)tg * D_DIM + d];
    const float xv  = xs[(size_t)tg * D_DIM + d];
    const float la = fminf(fmaxf(dtv * A, -20.f), 20.f);
    cum += la;
    e = __expf(cum);
    E[(size_t)tg * D_DIM + d] = e;
    const float u = __expf(-cum) * dtv * xv;
    const unsigned short ub = f2bf(u);
    if ((t & 1) == 0) pk[t >> 1] = (unsigned)ub;
    else              pk[t >> 1] |= ((unsigned)ub) << 16;
#pragma unroll
    for (int s4 = 0; s4 < 8; ++s4) {
      const float4 b = Bls[t * 8 + s4];
      vacc[s4 * 4 + 0] = fmaf(u, b.x, vacc[s4 * 4 + 0]);
      vacc[s4 * 4 + 1] = fmaf(u, b.y, vacc[s4 * 4 + 1]);
      vacc[s4 * 4 + 2] = fmaf(u, b.z, vacc[s4 * 4 + 2]);
      vacc[s4 * 4 + 3] = fmaf(u, b.w, vacc[s4 * 4 + 3]);
    }
  }
  {
    uint4* dst = reinterpret_cast<uint4*>(U_T + (size_t)d * T_LEN + c * CLEN);
    dst[0] = make_uint4(pk[0], pk[1], pk[2], pk[3]);
    dst[1] = make_uint4(pk[4], pk[5], pk[6], pk[7]);
    dst[2] = make_uint4(pk[8], pk[9], pk[10], pk[11]);
    dst[3] = make_uint4(pk[12], pk[13], pk[14], pk[15]);
  }
  {
    float4* dst = reinterpret_cast<float4*>(V + ((size_t)c * D_DIM + d) * 32);
#pragma unroll
    for (int s4 = 0; s4 < 8; ++s4)
      dst[s4] = make_float4(vacc[s4 * 4], vacc[s4 * 4 + 1], vacc[s4 * 4 + 2], vacc[s4 * 4 + 3]);
  }
  Pc[c * D_DIM + d] = e;
}

// ---------------------------------------------------------------------------
// Gram: Gm[c][t][t'] = (t'<=t) ? sum_s C[c,t,s]*B[c,t',s] : 0   (bf16)
// ---------------------------------------------------------------------------
__global__ __launch_bounds__(256) void gram_kernel(
    const float* __restrict__ Bm, const float* __restrict__ Cm,
    unsigned short* __restrict__ Gm) {
  const int c = blockIdx.x;
  __shared__ float Bls[32][33], Cls[32][33];
  {
    const int t = threadIdx.x >> 3;
    const int s4 = threadIdx.x & 7;
    const float4 b = reinterpret_cast<const float4*>(Bm + (c * CLEN + t) * 32)[s4];
    const float4 cc = reinterpret_cast<const float4*>(Cm + (c * CLEN + t) * 32)[s4];
    Bls[t][s4 * 4 + 0] = b.x;  Bls[t][s4 * 4 + 1] = b.y;
    Bls[t][s4 * 4 + 2] = b.z;  Bls[t][s4 * 4 + 3] = b.w;
    Cls[t][s4 * 4 + 0] = cc.x; Cls[t][s4 * 4 + 1] = cc.y;
    Cls[t][s4 * 4 + 2] = cc.z; Cls[t][s4 * 4 + 3] = cc.w;
  }
  __syncthreads();
  const int t = threadIdx.x >> 3;
  const int tp0 = (threadIdx.x & 7) * 4;
  float g[4];
#pragma unroll
  for (int q = 0; q < 4; ++q) {
    const int tp = tp0 + q;
    float acc = 0.f;
    if (tp <= t) {
#pragma unroll
      for (int s = 0; s < 32; ++s) acc = fmaf(Cls[t][s], Bls[tp][s], acc);
    }
    g[q] = acc;
  }
  ushort4 o;
  o.x = f2bf(g[0]); o.y = f2bf(g[1]); o.z = f2bf(g[2]); o.w = f2bf(g[3]);
  reinterpret_cast<ushort4*>(Gm + c * 1024)[threadIdx.x] = o;
}

// ---------------------------------------------------------------------------
// S2 state scan: Hin[c][d][s]; h_{c+1} = Pc[c][d]*(h_c + V[c][d][s])
// ---------------------------------------------------------------------------
__global__ __launch_bounds__(256) void state_scan_kernel(
    const float* __restrict__ V, const float* __restrict__ Pc,
    float* __restrict__ Hin) {
  const int gt = blockIdx.x * 256 + threadIdx.x;  // d*32+s
  const int d = gt >> 5;
  float h = 0.f;
  for (int c = 0; c < NCHUNK; ++c) {
    Hin[c * 16384 + gt] = h;
    h = Pc[c * D_DIM + d] * (h + V[c * 16384 + gt]);
  }
}

// ---------------------------------------------------------------------------
// S3: per (chunk c, dtile): acc = [Gm|C_c] @ [U_T ; Hin]
//   y[t,d] = E[t,d] * acc;  g = (y + xs*Dp)*silu(z) -> bf16  (gate fused)
// ---------------------------------------------------------------------------
__global__ __launch_bounds__(256) void ssm_out_kernel(
    const unsigned short* __restrict__ Gm, const unsigned short* __restrict__ U_T,
    const float* __restrict__ Hin, const float* __restrict__ Cm,
    const float* __restrict__ E, const float* __restrict__ xs,
    const float* __restrict__ Dp, const float* __restrict__ xz,
    unsigned short* __restrict__ g) {
  const int c = blockIdx.x;
  const int dt0 = blockIdx.y * 64;
  __shared__ bf16x8 Als[32 * 8];
  __shared__ bf16x8 Bls[64 * 8];
  const int tid = threadIdx.x;

  if (tid < 128) {
    const int t = tid >> 2, q = tid & 3;
    Als[t * 8 + (q ^ (t & 7))] =
        *reinterpret_cast<const bf16x8*>(Gm + c * 1024 + t * 32 + q * 8);
  } else {
    const int i = tid - 128;
    const int t = i >> 2, q = i & 3;
    const float* cp = Cm + (c * CLEN + t) * 32 + q * 8;
    const float4 c0 = *reinterpret_cast<const float4*>(cp);
    const float4 c1 = *reinterpret_cast<const float4*>(cp + 4);
    union { bf16x8 v; unsigned short u[8]; } wv;
    wv.u[0] = f2bf(c0.x); wv.u[1] = f2bf(c0.y); wv.u[2] = f2bf(c0.z); wv.u[3] = f2bf(c0.w);
    wv.u[4] = f2bf(c1.x); wv.u[5] = f2bf(c1.y); wv.u[6] = f2bf(c1.z); wv.u[7] = f2bf(c1.w);
    Als[t * 8 + ((4 + q) ^ (t & 7))] = wv.v;
  }
  {
    const int dd = tid >> 2, q = tid & 3;
    Bls[dd * 8 + (q ^ (dd & 7))] = *reinterpret_cast<const bf16x8*>(
        U_T + (size_t)(dt0 + dd) * T_LEN + c * CLEN + q * 8);
    const float* hp = Hin + ((size_t)c * D_DIM + dt0 + dd) * 32 + q * 8;
    const float4 h0 = *reinterpret_cast<const float4*>(hp);
    const float4 h1 = *reinterpret_cast<const float4*>(hp + 4);
    union { bf16x8 v; unsigned short u[8]; } wv;
    wv.u[0] = f2bf(h0.x); wv.u[1] = f2bf(h0.y); wv.u[2] = f2bf(h0.z); wv.u[3] = f2bf(h0.w);
    wv.u[4] = f2bf(h1.x); wv.u[5] = f2bf(h1.y); wv.u[6] = f2bf(h1.z); wv.u[7] = f2bf(h1.w);
    Bls[dd * 8 + ((4 + q) ^ (dd & 7))] = wv.v;
  }
  __syncthreads();

  const int lane = tid & 63;
  const int w = tid >> 6;
  const int wcol = w * 16;
  f32x4 acc[2];
  acc[0] = {0.f, 0.f, 0.f, 0.f};
  acc[1] = {0.f, 0.f, 0.f, 0.f};
#pragma unroll
  for (int kk = 0; kk < 2; ++kk) {
    const int slot = kk * 4 + (lane >> 4);
    const int rb = wcol + (lane & 15);
    const bf16x8 bfrag = Bls[rb * 8 + (slot ^ (rb & 7))];
#pragma unroll
    for (int m = 0; m < 2; ++m) {
      const int r = m * 16 + (lane & 15);
      const bf16x8 afrag = Als[r * 8 + (slot ^ (r & 7))];
      acc[m] = __builtin_amdgcn_mfma_f32_16x16x32_bf16(afrag, bfrag, acc[m], 0, 0, 0);
    }
  }
  const int dg = dt0 + wcol + (lane & 15);
  const float dpv = Dp[dg];
#pragma unroll
  for (int m = 0; m < 2; ++m) {
#pragma unroll
    for (int j = 0; j < 4; ++j) {
      const int tg = c * CLEN + m * 16 + (lane >> 4) * 4 + j;
      const float y = E[(size_t)tg * D_DIM + dg] * acc[m][j];
      const float xv = xs[(size_t)tg * D_DIM + dg];
      const float zv = xz[(size_t)tg * 1024 + 512 + dg];
      g[(size_t)tg * D_DIM + dg] = f2bf(fmaf(xv, dpv, y) * silu_f(zv));
    }
  }
}

// ---------------------------------------------------------------------------
extern "C" void kernel_launch(void* const* d_in, const int* in_sizes, int n_in,
                              void* d_out, int out_size, void* d_ws, size_t ws_size,
                              hipStream_t stream) {
  const float* x      = (const float*)d_in[0];
  const float* norm_w = (const float*)d_in[1];
  const float* W_in   = (const float*)d_in[2];
  const float* conv_w = (const float*)d_in[3];
  const float* conv_b = (const float*)d_in[4];
  const float* W_dt   = (const float*)d_in[5];
  const float* b_dt   = (const float*)d_in[6];
  const float* W_B    = (const float*)d_in[7];
  const float* W_C    = (const float*)d_in[8];
  const float* W_out  = (const float*)d_in[9];
  const float* log_A  = (const float*)d_in[10];
  const float* D_par  = (const float*)d_in[11];
  const float* W_ffn1 = (const float*)d_in[12];
  const float* W_ffn2 = (const float*)d_in[13];
  const float* W_mrg  = (const float*)d_in[14];
  float* out = (float*)d_out;

  const size_t M1 = 1u << 20;
  char* ws = (char*)d_ws;
  size_t off = 0;
  auto alloc_f = [&](size_t n) { float* p = (float*)(ws + off); off += n * 4; return p; };
  auto alloc_h = [&](size_t n) { unsigned short* p = (unsigned short*)(ws + off); off += n * 2; return p; };

  float* xz  = alloc_f(2 * M1);   // [2048][1024]
  float* xs  = alloc_f(M1);
  float* dt  = alloc_f(M1);
  float* E   = alloc_f(M1);
  float* V   = alloc_f(M1);       // [64][512][32]
  float* Hin = alloc_f(M1);       // [64][512][32]
  float* Bm  = alloc_f(1 << 16);
  float* Cm  = alloc_f(1 << 16);
  float* Pc  = alloc_f(NCHUNK * D_DIM);
  unsigned short* U_T    = alloc_h(M1);          // [512][2048]
  unsigned short* Gm     = alloc_h(NCHUNK * 1024);
  unsigned short* xn_bf  = alloc_h(M1);
  unsigned short* xs_bf  = alloc_h(M1);
  unsigned short* g_bf   = alloc_h(M1);
  unsigned short* h1_bf  = alloc_h(2 * M1);      // [2048][1024]
  unsigned short* cat_bf = alloc_h(2 * M1);      // [2048][1024] = [yssm|yffn]
  unsigned short* WinF1T = alloc_h(2048 * 512);  // rows: W_in cols (1024) ++ W_ffn1 cols (1024)
  unsigned short* WdtBCT = alloc_h(576 * 512);   // rows: W_dt (512) ++ W_B (32) ++ W_C (32)
  unsigned short* WoutT  = alloc_h(512 * 512);
  unsigned short* Wf2T   = alloc_h(512 * 1024);
  unsigned short* WmT    = alloc_h(512 * 1024);

  // --- weight prep (transpose to [N][K] bf16) ---
  transpose_bf16_kernel<<<dim3(32, 16), 256, 0, stream>>>(W_in,   WinF1T,              512, 1024);
  transpose_bf16_kernel<<<dim3(32, 16), 256, 0, stream>>>(W_ffn1, WinF1T + 1024 * 512, 512, 1024);
  transpose_bf16_kernel<<<dim3(16, 16), 256, 0, stream>>>(W_dt,   WdtBCT,              512, 512);
  transpose_bf16_kernel<<<dim3(1, 16),  256, 0, stream>>>(W_B,    WdtBCT + 512 * 512,  512, 32);
  transpose_bf16_kernel<<<dim3(1, 16),  256, 0, stream>>>(W_C,    WdtBCT + 544 * 512,  512, 32);
  transpose_bf16_kernel<<<dim3(16, 16), 256, 0, stream>>>(W_out,  WoutT, 512, 512);
  transpose_bf16_kernel<<<dim3(16, 32), 256, 0, stream>>>(W_ffn2, Wf2T, 1024, 512);
  transpose_bf16_kernel<<<dim3(16, 32), 256, 0, stream>>>(W_mrg,  WmT,  1024, 512);

  // 1. RMSNorm -> bf16
  rmsnorm_kernel<<<T_LEN, 256, 0, stream>>>(x, norm_w, xn_bf);
  // 2. fused: [xz | h1] = xn @ [W_in | W_ffn1]  (N=2048, 1024 blocks)
  gemm_mfma<0><<<dim3(32, 32), 256, 0, stream>>>(
      xn_bf, WinF1T, xz, h1_bf, nullptr, 2048, 2048, 512, 0, nullptr, nullptr);
  // 3. conv + silu
  conv_silu_kernel<<<4096, 256, 0, stream>>>(xz, conv_w, conv_b, xs, xs_bf);
  // 4. fused: [dt | Bm | Cm] = xs @ [W_dt | W_B | W_C]  (N=576)
  gemm_mfma<1><<<dim3(9, 32), 256, 0, stream>>>(
      xs_bf, WdtBCT, dt, Bm, Cm, 2048, 576, 512, 0, b_dt, nullptr);
  // 5. chunk prep (S1)
  chunk_prep_kernel<<<dim3(NCHUNK, 2), 256, 0, stream>>>(dt, xs, Bm, log_A, U_T, E, V, Pc);
  // 6. gram matrices
  gram_kernel<<<NCHUNK, 256, 0, stream>>>(Bm, Cm, Gm);
  // 7. inter-chunk state scan (S2)
  state_scan_kernel<<<64, 256, 0, stream>>>(V, Pc, Hin);
  // 8. intra+inter output + fused gate (S3) -> g_bf
  ssm_out_kernel<<<dim3(NCHUNK, 8), 256, 0, stream>>>(Gm, U_T, Hin, Cm, E, xs, D_par, xz, g_bf);
  // 9. cat[:, :512] = g @ W_out (bf16, ld 1024)
  gemm_mfma<2><<<dim3(8, 32), 256, 0, stream>>>(
      g_bf, WoutT, cat_bf, nullptr, nullptr, 2048, 512, 512, 1024, nullptr, nullptr);
  // 10. cat[:, 512:] = h1 @ W_ffn2 (bf16, ld 1024)
  gemm_mfma<2><<<dim3(8, 32), 256, 0, stream>>>(
      h1_bf, Wf2T, cat_bf + 512, nullptr, nullptr, 2048, 512, 1024, 1024, nullptr, nullptr);
  // 11. out = x + cat @ W_mrg  (K=1024, residual fused)
  gemm_mfma<3><<<dim3(8, 32), 256, 0, stream>>>(
      cat_bf, WmT, out, nullptr, nullptr, 2048, 512, 1024, 0, nullptr, x);
}

// Round 6
// 90.225 us; speedup vs baseline: 8.5516x; 1.2883x over previous
//
#include <hip/hip_runtime.h>
#include <math.h>

// Problem constants: B=1, T=2048, D=512, DS=32, EXP=2
#define T_LEN 2048
#define D_DIM 512
#define NCHUNK 64
#define CLEN 32

typedef __bf16 bf16x8 __attribute__((ext_vector_type(8)));
typedef float f32x4 __attribute__((ext_vector_type(4)));

__device__ __forceinline__ float silu_f(float x) { return x / (1.f + __expf(-x)); }
__device__ __forceinline__ float softplus_f(float x) {
  return fmaxf(x, 0.f) + log1pf(__expf(-fabsf(x)));
}
__device__ __forceinline__ float gelu_f(float x) {
  return 0.5f * x * (1.f + erff(x * 0.70710678118654752440f));
}
__device__ __forceinline__ unsigned short f2bf(float f) {
  union { float f; unsigned u; } v; v.f = f;
  unsigned r = v.u + 0x7FFF + ((v.u >> 16) & 1);  // round-nearest-even
  return (unsigned short)(r >> 16);
}

// ---------------------------------------------------------------------------
// RMSNorm -> bf16
// ---------------------------------------------------------------------------
__global__ __launch_bounds__(256) void rmsnorm_kernel(
    const float* __restrict__ x, const float* __restrict__ w,
    unsigned short* __restrict__ xn) {
  const int t = blockIdx.x;
  const float2 v = reinterpret_cast<const float2*>(x + (size_t)t * D_DIM)[threadIdx.x];
  float ss = v.x * v.x + v.y * v.y;
#pragma unroll
  for (int m = 1; m < 64; m <<= 1) ss += __shfl_xor(ss, m);
  __shared__ float wsum[4];
  if ((threadIdx.x & 63) == 0) wsum[threadIdx.x >> 6] = ss;
  __syncthreads();
  const float tot = wsum[0] + wsum[1] + wsum[2] + wsum[3];
  const float scale = rsqrtf(tot * (1.f / D_DIM) + 1e-6f);
  const float2 wv = reinterpret_cast<const float2*>(w)[threadIdx.x];
  ushort2 o;
  o.x = f2bf(v.x * scale * wv.x);
  o.y = f2bf(v.y * scale * wv.y);
  reinterpret_cast<ushort2*>(xn + (size_t)t * D_DIM)[threadIdx.x] = o;
}

// ---------------------------------------------------------------------------
// Fused weight prep: 8 transpose+bf16 jobs in ONE launch.
// Each job: src f32 [K,N] -> dst bf16 [N,K]; 32x32 tiles.
// ---------------------------------------------------------------------------
struct TransJobs {
  const float* src[8];
  unsigned short* dst[8];
  int K[8];
  int N[8];
  int b0[9];  // block range starts; b0[8] = total blocks
};

__global__ __launch_bounds__(256) void prep_weights_kernel(TransJobs J) {
  __shared__ float tile[32][33];
  const int b = blockIdx.x;
  int ji = 0;
#pragma unroll
  for (int i = 1; i < 8; ++i) ji += (b >= J.b0[i]) ? 1 : 0;
  const float* __restrict__ src = J.src[ji];
  unsigned short* __restrict__ dst = J.dst[ji];
  const int K = J.K[ji], N = J.N[ji];
  const int rel = b - J.b0[ji];
  const int nbx = N >> 5;
  const int bx = rel % nbx, by = rel / nbx;
  const int k0 = by * 32, n0 = bx * 32;
  const int i = threadIdx.x & 31;
  const int r = threadIdx.x >> 5;
#pragma unroll
  for (int p = 0; p < 4; ++p) {
    const int kk = r + p * 8;
    tile[kk][i] = src[(size_t)(k0 + kk) * N + n0 + i];
  }
  __syncthreads();
#pragma unroll
  for (int p = 0; p < 4; ++p) {
    const int nn = r + p * 8;
    dst[(size_t)(n0 + nn) * K + k0 + i] = f2bf(tile[i][nn]);
  }
}

// ---------------------------------------------------------------------------
// bf16 MFMA GEMM (64x64 tile, BK=64, XOR-swizzled LDS, reg-staged prefetch)
// MODE 0 (INF1):  N=2048; col<1024 -> f32 O1[row*1024+col]; else gelu->bf16
//                 O2[row*1024+col-1024]
// MODE 1 (DTBC):  N=576; col<512 -> softplus(v+bias[col]) f32 O1[row*512+col];
//                 col 512..543 -> f32 O2[row*32+s]; 544..575 -> f32 O3[row*32+s]
// MODE 3 (MERGE): f32 O1[row*512+col] = resid[row*512+col] + v
// ---------------------------------------------------------------------------
template <int MODE>
__global__ __launch_bounds__(256) void gemm_mfma(
    const unsigned short* __restrict__ Abf, const unsigned short* __restrict__ Btbf,
    void* __restrict__ O1, void* __restrict__ O2, void* __restrict__ O3,
    int M, int N, int K, int ldC,
    const float* __restrict__ bias, const float* __restrict__ resid) {
  __shared__ bf16x8 As[512];
  __shared__ bf16x8 Bs[512];

  const int tid = threadIdx.x;
  const int lane = tid & 63;
  const int w = tid >> 6;
  const int wrow = (w >> 1) * 32;
  const int wcol = (w & 1) * 32;
  const int brow = blockIdx.y * 64;
  const int bcol = blockIdx.x * 64;
  const int K8 = K >> 3;

  const bf16x8* __restrict__ A8 = reinterpret_cast<const bf16x8*>(Abf);
  const bf16x8* __restrict__ B8 = reinterpret_cast<const bf16x8*>(Btbf);

  const int r0s = tid >> 3;
  const int c0s = tid & 7;

  f32x4 acc[2][2];
#pragma unroll
  for (int m = 0; m < 2; ++m)
#pragma unroll
    for (int n = 0; n < 2; ++n) acc[m][n] = {0.f, 0.f, 0.f, 0.f};

  const int nt = K >> 6;
  bf16x8 pa[2], pb[2];
#pragma unroll
  for (int p = 0; p < 2; ++p) {
    const int rr = r0s + p * 32;
    pa[p] = A8[(size_t)(brow + rr) * K8 + c0s];
    pb[p] = B8[(size_t)(bcol + rr) * K8 + c0s];
  }

  for (int t = 0; t < nt; ++t) {
#pragma unroll
    for (int p = 0; p < 2; ++p) {
      const int rr = r0s + p * 32;
      As[rr * 8 + (c0s ^ (rr & 7))] = pa[p];
      Bs[rr * 8 + (c0s ^ (rr & 7))] = pb[p];
    }
    __syncthreads();
    if (t + 1 < nt) {
      const int kb = (t + 1) * 8;
#pragma unroll
      for (int p = 0; p < 2; ++p) {
        const int rr = r0s + p * 32;
        pa[p] = A8[(size_t)(brow + rr) * K8 + kb + c0s];
        pb[p] = B8[(size_t)(bcol + rr) * K8 + kb + c0s];
      }
    }
#pragma unroll
    for (int kk = 0; kk < 2; ++kk) {
      const int slot = kk * 4 + (lane >> 4);
      bf16x8 af[2], bf_[2];
#pragma unroll
      for (int m = 0; m < 2; ++m) {
        const int r = wrow + m * 16 + (lane & 15);
        af[m] = As[r * 8 + (slot ^ (r & 7))];
      }
#pragma unroll
      for (int n = 0; n < 2; ++n) {
        const int r = wcol + n * 16 + (lane & 15);
        bf_[n] = Bs[r * 8 + (slot ^ (r & 7))];
      }
#pragma unroll
      for (int m = 0; m < 2; ++m)
#pragma unroll
        for (int n = 0; n < 2; ++n)
          acc[m][n] = __builtin_amdgcn_mfma_f32_16x16x32_bf16(af[m], bf_[n], acc[m][n], 0, 0, 0);
    }
    __syncthreads();
  }

#pragma unroll
  for (int m = 0; m < 2; ++m) {
#pragma unroll
    for (int n = 0; n < 2; ++n) {
      const int col = bcol + wcol + n * 16 + (lane & 15);
#pragma unroll
      for (int j = 0; j < 4; ++j) {
        const int row = brow + wrow + m * 16 + (lane >> 4) * 4 + j;
        float v = acc[m][n][j];
        if (MODE == 0) {
          if (col < 1024) {
            reinterpret_cast<float*>(O1)[(size_t)row * 1024 + col] = v;
          } else {
            reinterpret_cast<unsigned short*>(O2)[(size_t)row * 1024 + col - 1024] =
                f2bf(gelu_f(v));
          }
        } else if (MODE == 1) {
          if (col < 512) {
            reinterpret_cast<float*>(O1)[(size_t)row * 512 + col] =
                softplus_f(v + bias[col]);
          } else {
            const int s = col - 512;
            float* p = (s < 32) ? reinterpret_cast<float*>(O2)
                                : reinterpret_cast<float*>(O3);
            p[(size_t)row * 32 + (s & 31)] = v;
          }
        } else {  // MODE 3
          reinterpret_cast<float*>(O1)[(size_t)row * 512 + col] =
              resid[(size_t)row * 512 + col] + v;
        }
      }
    }
  }
}

// ---------------------------------------------------------------------------
// Dual GEMM: z=0: cat[:, :512] = g @ W_out (K=512)
//            z=1: cat[:, 512:] = h1 @ W_ffn2 (K=1024). ldC = 1024, bf16 out.
// ---------------------------------------------------------------------------
__global__ __launch_bounds__(256) void gemm_dual(
    const unsigned short* __restrict__ A0, const unsigned short* __restrict__ B0,
    int K0,
    const unsigned short* __restrict__ A1, const unsigned short* __restrict__ B1,
    int K1, unsigned short* __restrict__ cat) {
  __shared__ bf16x8 As[512];
  __shared__ bf16x8 Bs[512];

  const int z = blockIdx.z;
  const unsigned short* __restrict__ Abf = z ? A1 : A0;
  const unsigned short* __restrict__ Btbf = z ? B1 : B0;
  const int K = z ? K1 : K0;
  unsigned short* __restrict__ outp = cat + (z ? 512 : 0);

  const int tid = threadIdx.x;
  const int lane = tid & 63;
  const int w = tid >> 6;
  const int wrow = (w >> 1) * 32;
  const int wcol = (w & 1) * 32;
  const int brow = blockIdx.y * 64;
  const int bcol = blockIdx.x * 64;
  const int K8 = K >> 3;

  const bf16x8* __restrict__ A8 = reinterpret_cast<const bf16x8*>(Abf);
  const bf16x8* __restrict__ B8 = reinterpret_cast<const bf16x8*>(Btbf);

  const int r0s = tid >> 3;
  const int c0s = tid & 7;

  f32x4 acc[2][2];
#pragma unroll
  for (int m = 0; m < 2; ++m)
#pragma unroll
    for (int n = 0; n < 2; ++n) acc[m][n] = {0.f, 0.f, 0.f, 0.f};

  const int nt = K >> 6;
  bf16x8 pa[2], pb[2];
#pragma unroll
  for (int p = 0; p < 2; ++p) {
    const int rr = r0s + p * 32;
    pa[p] = A8[(size_t)(brow + rr) * K8 + c0s];
    pb[p] = B8[(size_t)(bcol + rr) * K8 + c0s];
  }

  for (int t = 0; t < nt; ++t) {
#pragma unroll
    for (int p = 0; p < 2; ++p) {
      const int rr = r0s + p * 32;
      As[rr * 8 + (c0s ^ (rr & 7))] = pa[p];
      Bs[rr * 8 + (c0s ^ (rr & 7))] = pb[p];
    }
    __syncthreads();
    if (t + 1 < nt) {
      const int kb = (t + 1) * 8;
#pragma unroll
      for (int p = 0; p < 2; ++p) {
        const int rr = r0s + p * 32;
        pa[p] = A8[(size_t)(brow + rr) * K8 + kb + c0s];
        pb[p] = B8[(size_t)(bcol + rr) * K8 + kb + c0s];
      }
    }
#pragma unroll
    for (int kk = 0; kk < 2; ++kk) {
      const int slot = kk * 4 + (lane >> 4);
      bf16x8 af[2], bf_[2];
#pragma unroll
      for (int m = 0; m < 2; ++m) {
        const int r = wrow + m * 16 + (lane & 15);
        af[m] = As[r * 8 + (slot ^ (r & 7))];
      }
#pragma unroll
      for (int n = 0; n < 2; ++n) {
        const int r = wcol + n * 16 + (lane & 15);
        bf_[n] = Bs[r * 8 + (slot ^ (r & 7))];
      }
#pragma unroll
      for (int m = 0; m < 2; ++m)
#pragma unroll
        for (int n = 0; n < 2; ++n)
          acc[m][n] = __builtin_amdgcn_mfma_f32_16x16x32_bf16(af[m], bf_[n], acc[m][n], 0, 0, 0);
    }
    __syncthreads();
  }

#pragma unroll
  for (int m = 0; m < 2; ++m) {
#pragma unroll
    for (int n = 0; n < 2; ++n) {
      const int col = bcol + wcol + n * 16 + (lane & 15);
#pragma unroll
      for (int j = 0; j < 4; ++j) {
        const int row = brow + wrow + m * 16 + (lane >> 4) * 4 + j;
        outp[(size_t)row * 1024 + col] = f2bf(acc[m][n][j]);
      }
    }
  }
}

// ---------------------------------------------------------------------------
// Causal depthwise conv (k=4) + bias + SiLU -> f32 + bf16
// ---------------------------------------------------------------------------
__global__ __launch_bounds__(256) void conv_silu_kernel(
    const float* __restrict__ xz, const float* __restrict__ cw,
    const float* __restrict__ cb, float* __restrict__ xs,
    unsigned short* __restrict__ xs_bf) {
  const int idx = blockIdx.x * 256 + threadIdx.x;
  const int t = idx >> 9;
  const int d = idx & 511;
  const float4 w = reinterpret_cast<const float4*>(cw)[d];
  float acc = cb[d];
  const float wk[4] = {w.x, w.y, w.z, w.w};
#pragma unroll
  for (int k = 0; k < 4; ++k) {
    const int tt = t - 3 + k;
    if (tt >= 0) acc = fmaf(xz[(size_t)tt * 1024 + d], wk[k], acc);
  }
  const float s = silu_f(acc);
  xs[idx] = s;
  xs_bf[idx] = f2bf(s);
}

// ---------------------------------------------------------------------------
// Fused S1 chunk prep (blocks 0..127) + Gram (blocks 128..191), one launch.
// chunk_prep per (c, dgroup): cum/E/u/U_T/V/Pc.  gram per c: Gm.
// ---------------------------------------------------------------------------
__global__ __launch_bounds__(256) void prep_gram_kernel(
    const float* __restrict__ dt, const float* __restrict__ xs,
    const float* __restrict__ Bm, const float* __restrict__ Cm,
    const float* __restrict__ log_A,
    unsigned short* __restrict__ U_T, float* __restrict__ E,
    float* __restrict__ V, float* __restrict__ Pc,
    unsigned short* __restrict__ Gm) {
  __shared__ float4 Bls4[CLEN * 8];
  __shared__ float Bls[32][33], Cls[32][33];

  if (blockIdx.x < 128) {
    // ---- chunk_prep ----
    const int c = blockIdx.x >> 1;
    const int d = (blockIdx.x & 1) * 256 + threadIdx.x;
    Bls4[threadIdx.x] = reinterpret_cast<const float4*>(Bm + c * CLEN * 32)[threadIdx.x];
    __syncthreads();

    const float A = -__expf(log_A[d]);
    float cum = 0.f;
    float e = 1.f;
    float vacc[32];
#pragma unroll
    for (int s = 0; s < 32; ++s) vacc[s] = 0.f;
    unsigned pk[16];
#pragma unroll
    for (int t = 0; t < CLEN; ++t) {
      const int tg = c * CLEN + t;
      const float dtv = dt[(size_t)tg * D_DIM + d];
      const float xv  = xs[(size_t)tg * D_DIM + d];
      const float la = fminf(fmaxf(dtv * A, -20.f), 20.f);
      cum += la;
      e = __expf(cum);
      E[(size_t)tg * D_DIM + d] = e;
      const float u = __expf(-cum) * dtv * xv;
      const unsigned short ub = f2bf(u);
      if ((t & 1) == 0) pk[t >> 1] = (unsigned)ub;
      else              pk[t >> 1] |= ((unsigned)ub) << 16;
#pragma unroll
      for (int s4 = 0; s4 < 8; ++s4) {
        const float4 b = Bls4[t * 8 + s4];
        vacc[s4 * 4 + 0] = fmaf(u, b.x, vacc[s4 * 4 + 0]);
        vacc[s4 * 4 + 1] = fmaf(u, b.y, vacc[s4 * 4 + 1]);
        vacc[s4 * 4 + 2] = fmaf(u, b.z, vacc[s4 * 4 + 2]);
        vacc[s4 * 4 + 3] = fmaf(u, b.w, vacc[s4 * 4 + 3]);
      }
    }
    {
      uint4* dst = reinterpret_cast<uint4*>(U_T + (size_t)d * T_LEN + c * CLEN);
      dst[0] = make_uint4(pk[0], pk[1], pk[2], pk[3]);
      dst[1] = make_uint4(pk[4], pk[5], pk[6], pk[7]);
      dst[2] = make_uint4(pk[8], pk[9], pk[10], pk[11]);
      dst[3] = make_uint4(pk[12], pk[13], pk[14], pk[15]);
    }
    {
      float4* dst = reinterpret_cast<float4*>(V + ((size_t)c * D_DIM + d) * 32);
#pragma unroll
      for (int s4 = 0; s4 < 8; ++s4)
        dst[s4] = make_float4(vacc[s4 * 4], vacc[s4 * 4 + 1], vacc[s4 * 4 + 2], vacc[s4 * 4 + 3]);
    }
    Pc[c * D_DIM + d] = e;
  } else {
    // ---- gram ----
    const int c = blockIdx.x - 128;
    {
      const int t = threadIdx.x >> 3;
      const int s4 = threadIdx.x & 7;
      const float4 b = reinterpret_cast<const float4*>(Bm + (c * CLEN + t) * 32)[s4];
      const float4 cc = reinterpret_cast<const float4*>(Cm + (c * CLEN + t) * 32)[s4];
      Bls[t][s4 * 4 + 0] = b.x;  Bls[t][s4 * 4 + 1] = b.y;
      Bls[t][s4 * 4 + 2] = b.z;  Bls[t][s4 * 4 + 3] = b.w;
      Cls[t][s4 * 4 + 0] = cc.x; Cls[t][s4 * 4 + 1] = cc.y;
      Cls[t][s4 * 4 + 2] = cc.z; Cls[t][s4 * 4 + 3] = cc.w;
    }
    __syncthreads();
    const int t = threadIdx.x >> 3;
    const int tp0 = (threadIdx.x & 7) * 4;
    float g[4];
#pragma unroll
    for (int q = 0; q < 4; ++q) {
      const int tp = tp0 + q;
      float acc = 0.f;
      if (tp <= t) {
#pragma unroll
        for (int s = 0; s < 32; ++s) acc = fmaf(Cls[t][s], Bls[tp][s], acc);
      }
      g[q] = acc;
    }
    ushort4 o;
    o.x = f2bf(g[0]); o.y = f2bf(g[1]); o.z = f2bf(g[2]); o.w = f2bf(g[3]);
    reinterpret_cast<ushort4*>(Gm + c * 1024)[threadIdx.x] = o;
  }
}

// ---------------------------------------------------------------------------
// S2 state scan: Hin[c][d][s]; h_{c+1} = Pc[c][d]*(h_c + V[c][d][s])
// ---------------------------------------------------------------------------
__global__ __launch_bounds__(256) void state_scan_kernel(
    const float* __restrict__ V, const float* __restrict__ Pc,
    float* __restrict__ Hin) {
  const int gt = blockIdx.x * 256 + threadIdx.x;  // d*32+s
  const int d = gt >> 5;
  float h = 0.f;
  for (int c = 0; c < NCHUNK; ++c) {
    Hin[c * 16384 + gt] = h;
    h = Pc[c * D_DIM + d] * (h + V[c * 16384 + gt]);
  }
}

// ---------------------------------------------------------------------------
// S3: per (chunk c, dtile): acc = [Gm|C_c] @ [U_T ; Hin]
//   y[t,d] = E[t,d] * acc;  g = (y + xs*Dp)*silu(z) -> bf16  (gate fused)
// ---------------------------------------------------------------------------
__global__ __launch_bounds__(256) void ssm_out_kernel(
    const unsigned short* __restrict__ Gm, const unsigned short* __restrict__ U_T,
    const float* __restrict__ Hin, const float* __restrict__ Cm,
    const float* __restrict__ E, const float* __restrict__ xs,
    const float* __restrict__ Dp, const float* __restrict__ xz,
    unsigned short* __restrict__ g) {
  const int c = blockIdx.x;
  const int dt0 = blockIdx.y * 64;
  __shared__ bf16x8 Als[32 * 8];
  __shared__ bf16x8 Bls[64 * 8];
  const int tid = threadIdx.x;

  if (tid < 128) {
    const int t = tid >> 2, q = tid & 3;
    Als[t * 8 + (q ^ (t & 7))] =
        *reinterpret_cast<const bf16x8*>(Gm + c * 1024 + t * 32 + q * 8);
  } else {
    const int i = tid - 128;
    const int t = i >> 2, q = i & 3;
    const float* cp = Cm + (c * CLEN + t) * 32 + q * 8;
    const float4 c0 = *reinterpret_cast<const float4*>(cp);
    const float4 c1 = *reinterpret_cast<const float4*>(cp + 4);
    union { bf16x8 v; unsigned short u[8]; } wv;
    wv.u[0] = f2bf(c0.x); wv.u[1] = f2bf(c0.y); wv.u[2] = f2bf(c0.z); wv.u[3] = f2bf(c0.w);
    wv.u[4] = f2bf(c1.x); wv.u[5] = f2bf(c1.y); wv.u[6] = f2bf(c1.z); wv.u[7] = f2bf(c1.w);
    Als[t * 8 + ((4 + q) ^ (t & 7))] = wv.v;
  }
  {
    const int dd = tid >> 2, q = tid & 3;
    Bls[dd * 8 + (q ^ (dd & 7))] = *reinterpret_cast<const bf16x8*>(
        U_T + (size_t)(dt0 + dd) * T_LEN + c * CLEN + q * 8);
    const float* hp = Hin + ((size_t)c * D_DIM + dt0 + dd) * 32 + q * 8;
    const float4 h0 = *reinterpret_cast<const float4*>(hp);
    const float4 h1 = *reinterpret_cast<const float4*>(hp + 4);
    union { bf16x8 v; unsigned short u[8]; } wv;
    wv.u[0] = f2bf(h0.x); wv.u[1] = f2bf(h0.y); wv.u[2] = f2bf(h0.z); wv.u[3] = f2bf(h0.w);
    wv.u[4] = f2bf(h1.x); wv.u[5] = f2bf(h1.y); wv.u[6] = f2bf(h1.z); wv.u[7] = f2bf(h1.w);
    Bls[dd * 8 + ((4 + q) ^ (dd & 7))] = wv.v;
  }
  __syncthreads();

  const int lane = tid & 63;
  const int w = tid >> 6;
  const int wcol = w * 16;
  f32x4 acc[2];
  acc[0] = {0.f, 0.f, 0.f, 0.f};
  acc[1] = {0.f, 0.f, 0.f, 0.f};
#pragma unroll
  for (int kk = 0; kk < 2; ++kk) {
    const int slot = kk * 4 + (lane >> 4);
    const int rb = wcol + (lane & 15);
    const bf16x8 bfrag = Bls[rb * 8 + (slot ^ (rb & 7))];
#pragma unroll
    for (int m = 0; m < 2; ++m) {
      const int r = m * 16 + (lane & 15);
      const bf16x8 afrag = Als[r * 8 + (slot ^ (r & 7))];
      acc[m] = __builtin_amdgcn_mfma_f32_16x16x32_bf16(afrag, bfrag, acc[m], 0, 0, 0);
    }
  }
  const int dg = dt0 + wcol + (lane & 15);
  const float dpv = Dp[dg];
#pragma unroll
  for (int m = 0; m < 2; ++m) {
#pragma unroll
    for (int j = 0; j < 4; ++j) {
      const int tg = c * CLEN + m * 16 + (lane >> 4) * 4 + j;
      const float y = E[(size_t)tg * D_DIM + dg] * acc[m][j];
      const float xv = xs[(size_t)tg * D_DIM + dg];
      const float zv = xz[(size_t)tg * 1024 + 512 + dg];
      g[(size_t)tg * D_DIM + dg] = f2bf(fmaf(xv, dpv, y) * silu_f(zv));
    }
  }
}

// ---------------------------------------------------------------------------
extern "C" void kernel_launch(void* const* d_in, const int* in_sizes, int n_in,
                              void* d_out, int out_size, void* d_ws, size_t ws_size,
                              hipStream_t stream) {
  const float* x      = (const float*)d_in[0];
  const float* norm_w = (const float*)d_in[1];
  const float* W_in   = (const float*)d_in[2];
  const float* conv_w = (const float*)d_in[3];
  const float* conv_b = (const float*)d_in[4];
  const float* W_dt   = (const float*)d_in[5];
  const float* b_dt   = (const float*)d_in[6];
  const float* W_B    = (const float*)d_in[7];
  const float* W_C    = (const float*)d_in[8];
  const float* W_out  = (const float*)d_in[9];
  const float* log_A  = (const float*)d_in[10];
  const float* D_par  = (const float*)d_in[11];
  const float* W_ffn1 = (const float*)d_in[12];
  const float* W_ffn2 = (const float*)d_in[13];
  const float* W_mrg  = (const float*)d_in[14];
  float* out = (float*)d_out;

  const size_t M1 = 1u << 20;
  char* ws = (char*)d_ws;
  size_t off = 0;
  auto alloc_f = [&](size_t n) { float* p = (float*)(ws + off); off += n * 4; return p; };
  auto alloc_h = [&](size_t n) { unsigned short* p = (unsigned short*)(ws + off); off += n * 2; return p; };

  float* xz  = alloc_f(2 * M1);   // [2048][1024]
  float* xs  = alloc_f(M1);
  float* dt  = alloc_f(M1);
  float* E   = alloc_f(M1);
  float* V   = alloc_f(M1);       // [64][512][32]
  float* Hin = alloc_f(M1);       // [64][512][32]
  float* Bm  = alloc_f(1 << 16);
  float* Cm  = alloc_f(1 << 16);
  float* Pc  = alloc_f(NCHUNK * D_DIM);
  unsigned short* U_T    = alloc_h(M1);          // [512][2048]
  unsigned short* Gm     = alloc_h(NCHUNK * 1024);
  unsigned short* xn_bf  = alloc_h(M1);
  unsigned short* xs_bf  = alloc_h(M1);
  unsigned short* g_bf   = alloc_h(M1);
  unsigned short* h1_bf  = alloc_h(2 * M1);      // [2048][1024]
  unsigned short* cat_bf = alloc_h(2 * M1);      // [2048][1024] = [yssm|yffn]
  unsigned short* WinF1T = alloc_h(2048 * 512);  // W_in cols (1024) ++ W_ffn1 cols (1024)
  unsigned short* WdtBCT = alloc_h(576 * 512);   // W_dt (512) ++ W_B (32) ++ W_C (32)
  unsigned short* WoutT  = alloc_h(512 * 512);
  unsigned short* Wf2T   = alloc_h(512 * 1024);
  unsigned short* WmT    = alloc_h(512 * 1024);

  // --- fused weight prep (1 launch, 8 jobs) ---
  TransJobs J;
  J.src[0] = W_in;   J.dst[0] = WinF1T;              J.K[0] = 512;  J.N[0] = 1024;
  J.src[1] = W_ffn1; J.dst[1] = WinF1T + 1024 * 512; J.K[1] = 512;  J.N[1] = 1024;
  J.src[2] = W_dt;   J.dst[2] = WdtBCT;              J.K[2] = 512;  J.N[2] = 512;
  J.src[3] = W_B;    J.dst[3] = WdtBCT + 512 * 512;  J.K[3] = 512;  J.N[3] = 32;
  J.src[4] = W_C;    J.dst[4] = WdtBCT + 544 * 512;  J.K[4] = 512;  J.N[4] = 32;
  J.src[5] = W_out;  J.dst[5] = WoutT;               J.K[5] = 512;  J.N[5] = 512;
  J.src[6] = W_ffn2; J.dst[6] = Wf2T;                J.K[6] = 1024; J.N[6] = 512;
  J.src[7] = W_mrg;  J.dst[7] = WmT;                 J.K[7] = 1024; J.N[7] = 512;
  int bacc = 0;
  for (int i = 0; i < 8; ++i) {
    J.b0[i] = bacc;
    bacc += (J.N[i] >> 5) * (J.K[i] >> 5);
  }
  J.b0[8] = bacc;  // 2592
  prep_weights_kernel<<<bacc, 256, 0, stream>>>(J);

  // 1. RMSNorm -> bf16
  rmsnorm_kernel<<<T_LEN, 256, 0, stream>>>(x, norm_w, xn_bf);
  // 2. fused: [xz | h1] = xn @ [W_in | W_ffn1]  (N=2048, 1024 blocks)
  gemm_mfma<0><<<dim3(32, 32), 256, 0, stream>>>(
      xn_bf, WinF1T, xz, h1_bf, nullptr, 2048, 2048, 512, 0, nullptr, nullptr);
  // 3. conv + silu
  conv_silu_kernel<<<4096, 256, 0, stream>>>(xz, conv_w, conv_b, xs, xs_bf);
  // 4. fused: [dt | Bm | Cm] = xs @ [W_dt | W_B | W_C]  (N=576)
  gemm_mfma<1><<<dim3(9, 32), 256, 0, stream>>>(
      xs_bf, WdtBCT, dt, Bm, Cm, 2048, 576, 512, 0, b_dt, nullptr);
  // 5. fused chunk prep + gram (192 blocks)
  prep_gram_kernel<<<192, 256, 0, stream>>>(dt, xs, Bm, Cm, log_A, U_T, E, V, Pc, Gm);
  // 6. inter-chunk state scan (S2)
  state_scan_kernel<<<64, 256, 0, stream>>>(V, Pc, Hin);
  // 7. intra+inter output + fused gate (S3) -> g_bf
  ssm_out_kernel<<<dim3(NCHUNK, 8), 256, 0, stream>>>(Gm, U_T, Hin, Cm, E, xs, D_par, xz, g_bf);
  // 8. dual GEMM: cat = [g @ W_out | h1 @ W_ffn2]
  gemm_dual<<<dim3(8, 32, 2), 256, 0, stream>>>(
      g_bf, WoutT, 512, h1_bf, Wf2T, 1024, cat_bf);
  // 9. out = x + cat @ W_mrg  (K=1024, residual fused)
  gemm_mfma<3><<<dim3(8, 32), 256, 0, stream>>>(
      cat_bf, WmT, out, nullptr, nullptr, 2048, 512, 1024, 0, nullptr, x);
}